// Round 2
// baseline (1354.244 us; speedup 1.0000x reference)
//
#include <hip/hip_runtime.h>
#include <math.h>

constexpr int DD    = 64;        // embedding dim
constexpr int KK    = 16;        // kg neighbors per item
constexpr int NUs   = 100000;    // users
constexpr int NIs   = 50000;     // items
constexpr int NEs   = 200000;    // entities
constexpr int NRs   = 64;        // relations
constexpr int NEDGE = 2000000;   // edges
constexpr int LAYERS = 2;
constexpr int BB    = 4096;      // batch
constexpr float REGf = 1e-4f;

__device__ __forceinline__ float wave_sum_f(float x) {
#pragma unroll
  for (int off = 32; off > 0; off >>= 1) x += __shfl_xor(x, off);
  return x;
}

// ---------------- CSR build ----------------

__global__ __launch_bounds__(256) void hist_kernel(const int* __restrict__ edge_u,
                                                   const int* __restrict__ edge_i,
                                                   int* cnt_u, int* cnt_i) {
  int stride = gridDim.x * blockDim.x;
  for (int e = blockIdx.x * blockDim.x + threadIdx.x; e < NEDGE; e += stride) {
    atomicAdd(&cnt_i[edge_i[e]], 1);
    atomicAdd(&cnt_u[edge_u[e]], 1);
  }
}

// one block per array: block 0 -> items (NIs), block 1 -> users (NUs)
// writes exclusive prefix into rp[], zeroes cnt[] for reuse as fill cursor,
// writes rp[n] = total.
__global__ __launch_bounds__(1024) void scan_kernel(int* cnt_i, int* rp_i,
                                                    int* cnt_u, int* rp_u) {
  int* cnt; int* rp; int n;
  if (blockIdx.x == 0) { cnt = cnt_i; rp = rp_i; n = NIs; }
  else                 { cnt = cnt_u; rp = rp_u; n = NUs; }
  __shared__ int wtot[16];
  __shared__ int srun;
  int tid = threadIdx.x;
  int lane = tid & 63, wid = tid >> 6;
  if (tid == 0) srun = 0;
  __syncthreads();
  for (int base = 0; base < n; base += 1024) {
    int i = base + tid;
    int x = (i < n) ? cnt[i] : 0;
    int v = x;
#pragma unroll
    for (int off = 1; off < 64; off <<= 1) {
      int y = __shfl_up(v, off);
      if (lane >= off) v += y;
    }
    if (lane == 63) wtot[wid] = v;
    __syncthreads();
    if (wid == 0) {
      int t = (lane < 16) ? wtot[lane] : 0;
#pragma unroll
      for (int off = 1; off < 16; off <<= 1) {
        int y = __shfl_up(t, off);
        if (lane >= off) t += y;
      }
      if (lane < 16) wtot[lane] = t;   // inclusive scan of wave totals
    }
    __syncthreads();
    int woff = (wid > 0) ? wtot[wid - 1] : 0;
    int excl = srun + woff + v - x;
    if (i < n) { rp[i] = excl; cnt[i] = 0; }
    int btot = wtot[15];
    __syncthreads();
    if (tid == 0) srun += btot;
    __syncthreads();
  }
  if (tid == 0) rp[n] = srun;
}

__global__ __launch_bounds__(256) void fill_kernel(const int* __restrict__ edge_u,
                                                   const int* __restrict__ edge_i,
                                                   const float* __restrict__ enorm,
                                                   const int* __restrict__ rp_i, int* cnt_i,
                                                   int* src_i, float* w_i,
                                                   const int* __restrict__ rp_u, int* cnt_u,
                                                   int* src_u, float* w_u) {
  int stride = gridDim.x * blockDim.x;
  for (int e = blockIdx.x * blockDim.x + threadIdx.x; e < NEDGE; e += stride) {
    int u = edge_u[e], it = edge_i[e];
    float w = enorm[e];
    int p = rp_i[it] + atomicAdd(&cnt_i[it], 1);
    src_i[p] = u;  w_i[p] = w;
    int q = rp_u[u] + atomicAdd(&cnt_u[u], 1);
    src_u[q] = it; w_u[q] = w;
  }
}

// ---------------- relation-space precompute ----------------
// Rt[l][n][d] = sum_o RE[n][o] * (Wk[l][o][d] + Wk[l][o][D+d])
// cvec[l][n]  = sum_o RE[n][o] * Wkb[l][o]
__global__ __launch_bounds__(64) void rt_kernel(const float* __restrict__ RE,
                                                const float* __restrict__ Wkw,
                                                const float* __restrict__ Wkb,
                                                float* Rt, float* cvec) {
  int l = blockIdx.x >> 6;
  int n = blockIdx.x & 63;
  int d = threadIdx.x;
  const float* W  = Wkw + (size_t)l * DD * 2 * DD;
  const float* re = RE + n * DD;
  float acc = 0.f;
  for (int o = 0; o < DD; ++o) {
    float w = W[o * 2 * DD + d] + W[o * 2 * DD + DD + d];
    acc += re[o] * w;
  }
  Rt[(l * NRs + n) * DD + d] = acc;
  float p = re[d] * Wkb[l * DD + d];
  p = wave_sum_f(p);
  if (d == 0) cvec[l * NRs + n] = p;
}

// ---------------- KG attention (one wave per item) ----------------
__global__ __launch_bounds__(256) void attn_kernel(const float* __restrict__ EE,
                                                   const float* __restrict__ Rt_l,
                                                   const float* __restrict__ c_l,
                                                   const int* __restrict__ kg_ent,
                                                   const int* __restrict__ kg_rel,
                                                   const float* __restrict__ i_cur,
                                                   float* __restrict__ kg_item) {
  __shared__ float rt_s[NRs * DD];   // 16 KiB
  __shared__ float c_s[NRs];
  for (int m = threadIdx.x; m < NRs * DD; m += blockDim.x) rt_s[m] = Rt_l[m];
  for (int m = threadIdx.x; m < NRs; m += blockDim.x) c_s[m] = c_l[m];
  __syncthreads();
  int lane = threadIdx.x & 63;
  int wid = threadIdx.x >> 6;
  int wpg = gridDim.x * (blockDim.x >> 6);
  for (int i = blockIdx.x * (blockDim.x >> 6) + wid; i < NIs; i += wpg) {
    float icur = i_cur[i * DD + lane];
    int eidx = 0, ridx = 0;
    if (lane < KK) { eidx = kg_ent[i * KK + lane]; ridx = kg_rel[i * KK + lane]; }
    float vk[KK];
    float sc[KK];
#pragma unroll
    for (int k = 0; k < KK; ++k) {
      int ent = __shfl(eidx, k);
      int rel = __shfl(ridx, k);
      float v = EE[ent * DD + lane];
      vk[k] = v;
      float p = v * icur * rt_s[rel * DD + lane];
      p = wave_sum_f(p);
      float s = p + c_s[rel];
      sc[k] = (s >= 0.f) ? s : 0.2f * s;   // leaky_relu 0.2
    }
    float m = sc[0];
#pragma unroll
    for (int k = 1; k < KK; ++k) m = fmaxf(m, sc[k]);
    float ssum = 0.f;
#pragma unroll
    for (int k = 0; k < KK; ++k) { sc[k] = __expf(sc[k] - m); ssum += sc[k]; }
    float inv = 1.f / ssum;
    float kg = 0.f;
#pragma unroll
    for (int k = 0; k < KK; ++k) kg += sc[k] * inv * vk[k];
    kg_item[i * DD + lane] = kg;
  }
}

// ---------------- fused dual-direction CSR segment-sum ----------------
// rows [0, NIs):       aggi[r]  = sum_j w_i[j] * embU[src_i[j]]
// rows [NIs, NIs+NUs): unext[r] = sum_j w_u[j] * embI[src_u[j]]
//                      usum[r]  = (usum_init ? usum_init[r] : usum[r]) + unext[r]
// Layout: 16 lanes x float4 cover one 256B row; 4 lane-groups process 4 edges
// at once; two independent accumulator chains (8 edges in flight / wave).
// Tail trick: lanes >= lim hold wj=0, and all shfl indices are provably <= 63,
// so out-of-range edge slots contribute w=0 * emb[row 0] = 0 (no predication).
__global__ __launch_bounds__(256) void agg2_kernel(
    const int* __restrict__ rp_i, const int* __restrict__ src_i, const float* __restrict__ w_i,
    const float* __restrict__ embU, float* __restrict__ aggi,
    const int* __restrict__ rp_u, const int* __restrict__ src_u, const float* __restrict__ w_u,
    const float* __restrict__ embI, float* __restrict__ unext,
    float* __restrict__ usum, const float* __restrict__ usum_init) {
  int lane = threadIdx.x & 63;
  int wid  = threadIdx.x >> 6;
  int sub  = lane & 15;   // which float4 of the row
  int grp  = lane >> 4;   // which of 4 concurrent edges
  int wpg  = gridDim.x * (blockDim.x >> 6);
  const int total = NIs + NUs;
  for (int row = blockIdx.x * (blockDim.x >> 6) + wid; row < total; row += wpg) {
    bool isU = row >= NIs;
    int r = isU ? (row - NIs) : row;
    const int*   rp  = isU ? rp_u  : rp_i;
    const int*   src = isU ? src_u : src_i;
    const float* wv  = isU ? w_u   : w_i;
    const float* emb = isU ? embI  : embU;
    int s0 = rp[r], s1 = rp[r + 1];
    float ax0 = 0.f, ay0 = 0.f, az0 = 0.f, aw0 = 0.f;
    float ax1 = 0.f, ay1 = 0.f, az1 = 0.f, aw1 = 0.f;
    for (int base = s0; base < s1; base += 64) {
      int lim = s1 - base; if (lim > 64) lim = 64;
      int sj = 0; float wj = 0.f;
      if (lane < lim) { sj = src[base + lane]; wj = wv[base + lane]; }
      for (int j = 0; j < lim; j += 8) {
        int m0 = j + grp;        // <= 59
        int m1 = j + 4 + grp;    // <= 63
        int   a0 = __shfl(sj, m0); float q0 = __shfl(wj, m0);
        int   a1 = __shfl(sj, m1); float q1 = __shfl(wj, m1);
        float4 e0 = reinterpret_cast<const float4*>(emb + ((size_t)a0 << 6))[sub];
        float4 e1 = reinterpret_cast<const float4*>(emb + ((size_t)a1 << 6))[sub];
        ax0 += q0 * e0.x; ay0 += q0 * e0.y; az0 += q0 * e0.z; aw0 += q0 * e0.w;
        ax1 += q1 * e1.x; ay1 += q1 * e1.y; az1 += q1 * e1.z; aw1 += q1 * e1.w;
      }
    }
    float ax = ax0 + ax1, ay = ay0 + ay1, az = az0 + az1, aw = aw0 + aw1;
    ax += __shfl_xor(ax, 16); ay += __shfl_xor(ay, 16);
    az += __shfl_xor(az, 16); aw += __shfl_xor(aw, 16);
    ax += __shfl_xor(ax, 32); ay += __shfl_xor(ay, 32);
    az += __shfl_xor(az, 32); aw += __shfl_xor(aw, 32);
    if (lane < 16) {
      float4 o; o.x = ax; o.y = ay; o.z = az; o.w = aw;
      if (!isU) {
        reinterpret_cast<float4*>(aggi + ((size_t)r << 6))[sub] = o;
      } else {
        reinterpret_cast<float4*>(unext + ((size_t)r << 6))[sub] = o;
        float4 si;
        if (usum_init) si = reinterpret_cast<const float4*>(usum_init + ((size_t)r << 6))[sub];
        else           si = reinterpret_cast<float4*>(usum + ((size_t)r << 6))[sub];
        float4 s; s.x = si.x + ax; s.y = si.y + ay; s.z = si.z + az; s.w = si.w + aw;
        reinterpret_cast<float4*>(usum + ((size_t)r << 6))[sub] = s;
      }
    }
  }
}

// ---------------- gate + item update (one wave per item) ----------------
__global__ __launch_bounds__(256) void gate_kernel(const float* __restrict__ Wa,
                                                   const float* __restrict__ Wab,
                                                   const float* __restrict__ Wb,
                                                   const float* __restrict__ Wbb,
                                                   const float* __restrict__ kg_item,
                                                   const float* __restrict__ agg_i,
                                                   const float* __restrict__ i_sum_init,
                                                   float* __restrict__ i_next,
                                                   float* __restrict__ i_sum) {
  __shared__ float at[DD * 65];   // transposed, padded (conflict-free)
  __shared__ float bt[DD * 65];
  for (int m = threadIdx.x; m < DD * DD; m += blockDim.x) {
    int o = m >> 6, d = m & 63;
    at[d * 65 + o] = Wa[m];
    bt[d * 65 + o] = Wb[m];
  }
  __syncthreads();
  int lane = threadIdx.x & 63, wid = threadIdx.x >> 6;
  int wpg = gridDim.x * (blockDim.x >> 6);
  float wab = Wab[lane], wbb = Wbb[lane];
  for (int i = blockIdx.x * (blockDim.x >> 6) + wid; i < NIs; i += wpg) {
    float kg = kg_item[i * DD + lane];
    float ag = agg_i[i * DD + lane];
    float acca = 0.f, accb = 0.f;
#pragma unroll
    for (int d = 0; d < DD; ++d) {
      float kd = __shfl(kg, d);
      float ad = __shfl(ag, d);
      acca += kd * at[d * 65 + lane];
      accb += ad * bt[d * 65 + lane];
    }
    float g = 1.f / (1.f + __expf(-(acca + wab + accb + wbb)));
    float inew = g * kg + (1.f - g) * ag;
    i_next[i * DD + lane] = inew;
    if (i_sum_init) i_sum[i * DD + lane] = i_sum_init[i * DD + lane] + inew;
    else            i_sum[i * DD + lane] += inew;
  }
}

// ---------------- BPR loss ----------------
__global__ __launch_bounds__(256) void loss_kernel(const float* __restrict__ u_sum,
                                                   const float* __restrict__ i_sum,
                                                   const int* __restrict__ user,
                                                   const int* __restrict__ pos,
                                                   const int* __restrict__ neg,
                                                   float* acc) {
  int lane = threadIdx.x & 63, wid = threadIdx.x >> 6;
  int wpg = gridDim.x * (blockDim.x >> 6);
  float lacc = 0.f, l2acc = 0.f;
  for (int b = blockIdx.x * (blockDim.x >> 6) + wid; b < BB; b += wpg) {
    float u = u_sum[user[b] * DD + lane];
    float p = i_sum[pos[b] * DD + lane];
    float n = i_sum[neg[b] * DD + lane];
    float ps = wave_sum_f(u * p);
    float ns = wave_sum_f(u * n);
    float sq = wave_sum_f(u * u + p * p + n * n);
    if (lane == 0) {
      float x = ps - ns;
      float sig = 1.f / (1.f + expf(-x));
      lacc += logf(sig + 1e-10f);
      l2acc += sq;
    }
  }
  if (lane == 0) {
    atomicAdd(&acc[0], lacc);
    atomicAdd(&acc[1], l2acc);
  }
}

__global__ void final_kernel(const float* acc, float* out) {
  out[0] = -acc[0] / (float)BB + REGf * (acc[1] / (float)BB);
}

// ---------------- host ----------------

extern "C" void kernel_launch(void* const* d_in, const int* in_sizes, int n_in,
                              void* d_out, int out_size, void* d_ws, size_t ws_size,
                              hipStream_t stream) {
  const float* UE   = (const float*)d_in[0];
  const float* IE   = (const float*)d_in[1];
  const float* EE   = (const float*)d_in[2];
  const float* RE   = (const float*)d_in[3];
  const float* Wkw  = (const float*)d_in[4];
  const float* Wkb  = (const float*)d_in[5];
  const float* Waw  = (const float*)d_in[6];
  const float* Wab  = (const float*)d_in[7];
  const float* Wbw  = (const float*)d_in[8];
  const float* Wbb  = (const float*)d_in[9];
  const float* enorm = (const float*)d_in[10];
  const int* user   = (const int*)d_in[11];
  const int* pos    = (const int*)d_in[12];
  const int* neg    = (const int*)d_in[13];
  const int* edge_u = (const int*)d_in[14];
  const int* edge_i = (const int*)d_in[15];
  const int* kg_rel = (const int*)d_in[16];
  const int* kg_ent = (const int*)d_in[17];

  size_t off = 0;
  char* base = (char*)d_ws;
  auto take = [&](size_t bytes) -> void* {
    void* p = base + off;
    off += (bytes + 255) & ~(size_t)255;
    return p;
  };
  float* Rt    = (float*)take(LAYERS * NRs * DD * sizeof(float));
  float* cvec  = (float*)take(LAYERS * NRs * sizeof(float));
  float* acc   = (float*)take(8 * sizeof(float));
  int*   cnt_i = (int*)take(NIs * sizeof(int));
  int*   cnt_u = (int*)take(NUs * sizeof(int));
  int*   rp_i  = (int*)take((NIs + 1) * sizeof(int));
  int*   rp_u  = (int*)take((NUs + 1) * sizeof(int));
  int*   src_i = (int*)take((size_t)NEDGE * sizeof(int));
  float* w_i   = (float*)take((size_t)NEDGE * sizeof(float));
  int*   src_u = (int*)take((size_t)NEDGE * sizeof(int));
  float* w_u   = (float*)take((size_t)NEDGE * sizeof(float));
  float* kg    = (float*)take((size_t)NIs * DD * sizeof(float));
  float* aggi  = (float*)take((size_t)NIs * DD * sizeof(float));
  float* iA    = (float*)take((size_t)NIs * DD * sizeof(float));
  float* iB    = (float*)take((size_t)NIs * DD * sizeof(float));
  float* isum  = (float*)take((size_t)NIs * DD * sizeof(float));
  float* uA    = (float*)take((size_t)NUs * DD * sizeof(float));
  float* uB    = (float*)take((size_t)NUs * DD * sizeof(float));
  float* usum  = (float*)take((size_t)NUs * DD * sizeof(float));
  (void)ws_size; (void)in_sizes; (void)n_in; (void)out_size;

  hipMemsetAsync(cnt_i, 0, NIs * sizeof(int), stream);
  hipMemsetAsync(cnt_u, 0, NUs * sizeof(int), stream);
  hipMemsetAsync(acc, 0, 8 * sizeof(float), stream);

  hist_kernel<<<2048, 256, 0, stream>>>(edge_u, edge_i, cnt_u, cnt_i);
  scan_kernel<<<2, 1024, 0, stream>>>(cnt_i, rp_i, cnt_u, rp_u);
  fill_kernel<<<2048, 256, 0, stream>>>(edge_u, edge_i, enorm,
                                        rp_i, cnt_i, src_i, w_i,
                                        rp_u, cnt_u, src_u, w_u);
  rt_kernel<<<LAYERS * NRs, 64, 0, stream>>>(RE, Wkw, Wkb, Rt, cvec);

  const float* u_cur = UE;
  const float* i_cur = IE;
  float* unext[2] = {uA, uB};
  float* inext[2] = {iA, iB};
  for (int l = 0; l < LAYERS; ++l) {
    attn_kernel<<<2048, 256, 0, stream>>>(EE, Rt + l * NRs * DD, cvec + l * NRs,
                                          kg_ent, kg_rel, i_cur, kg);
    // fused: agg_i (items) + agg_u/u_next/u_sum (users) in one dispatch
    agg2_kernel<<<2048, 256, 0, stream>>>(rp_i, src_i, w_i, u_cur, aggi,
                                          rp_u, src_u, w_u, i_cur, unext[l],
                                          usum, (l == 0) ? UE : nullptr);
    // gate + item update + fused i_sum update
    gate_kernel<<<2048, 256, 0, stream>>>(Waw + (size_t)l * DD * DD, Wab + l * DD,
                                          Wbw + (size_t)l * DD * DD, Wbb + l * DD,
                                          kg, aggi, (l == 0) ? IE : nullptr,
                                          inext[l], isum);
    u_cur = unext[l];
    i_cur = inext[l];
  }

  loss_kernel<<<1024, 256, 0, stream>>>(usum, isum, user, pos, neg, acc);
  final_kernel<<<1, 1, 0, stream>>>(acc, (float*)d_out);
}

// Round 3
// 1226.628 us; speedup vs baseline: 1.1040x; 1.1040x over previous
//
#include <hip/hip_runtime.h>
#include <math.h>

constexpr int DD    = 64;        // embedding dim
constexpr int KK    = 16;        // kg neighbors per item
constexpr int NUs   = 100000;    // users
constexpr int NIs   = 50000;     // items
constexpr int NEs   = 200000;    // entities
constexpr int NRs   = 64;        // relations
constexpr int NEDGE = 2000000;   // edges
constexpr int LAYERS = 2;
constexpr int BB    = 4096;      // batch
constexpr float REGf = 1e-4f;

constexpr int CHUNK = 4096;                       // scan chunk per block
constexpr int NCH_I = (NIs + CHUNK - 1) / CHUNK;  // 13
constexpr int NCH_U = (NUs + CHUNK - 1) / CHUNK;  // 25

__device__ __forceinline__ float wave_sum_f(float x) {
#pragma unroll
  for (int off = 32; off > 0; off >>= 1) x += __shfl_xor(x, off);
  return x;
}

// ---------------- CSR build ----------------

__global__ __launch_bounds__(256) void hist_kernel(const int* __restrict__ edge_u,
                                                   const int* __restrict__ edge_i,
                                                   int* cnt_u, int* cnt_i) {
  int stride = gridDim.x * blockDim.x;
  for (int e = blockIdx.x * blockDim.x + threadIdx.x; e < NEDGE; e += stride) {
    atomicAdd(&cnt_i[edge_i[e]], 1);
    atomicAdd(&cnt_u[edge_u[e]], 1);
  }
}

// chunk-local exclusive scan: block cb handles 4096 elements of cnt_i (cb < NCH_I)
// or cnt_u; writes within-chunk exclusive prefix into rp, chunk total into chtot.
__global__ __launch_bounds__(256) void scan1_kernel(const int* __restrict__ cnt_i,
                                                    const int* __restrict__ cnt_u,
                                                    int* rp_i, int* rp_u, int* chtot) {
  int cb = blockIdx.x;
  const int* cnt; int* rp; int n; int base;
  if (cb < NCH_I) { cnt = cnt_i; rp = rp_i; n = NIs; base = cb * CHUNK; }
  else            { cnt = cnt_u; rp = rp_u; n = NUs; base = (cb - NCH_I) * CHUNK; }
  int tid = threadIdx.x;
  int start = base + tid * 16;
  int vals[16];
  int s = 0;
#pragma unroll
  for (int j = 0; j < 16; ++j) {
    int idx = start + j;
    int v = (idx < n) ? cnt[idx] : 0;
    vals[j] = s;              // exclusive within-thread
    s += v;
  }
  int lane = tid & 63, wid = tid >> 6;
  int v = s;
#pragma unroll
  for (int off = 1; off < 64; off <<= 1) {
    int y = __shfl_up(v, off);
    if (lane >= off) v += y;
  }
  __shared__ int wt[4];
  if (lane == 63) wt[wid] = v;
  __syncthreads();
  int woff = 0;
#pragma unroll
  for (int w = 0; w < 4; ++w) if (w < wid) woff += wt[w];
  int texcl = woff + v - s;   // exclusive prefix of this thread's total within chunk
#pragma unroll
  for (int j = 0; j < 16; ++j) {
    int idx = start + j;
    if (idx < n) rp[idx] = texcl + vals[j];
  }
  if (tid == 255) chtot[cb] = woff + v;   // chunk total
}

// one wave: segmented exclusive scan of the 38 chunk totals (items | users)
__global__ __launch_bounds__(64) void scan2_kernel(int* chtot) {
  int lane = threadIdx.x;
  const int nc = NCH_I + NCH_U;
  int x = (lane < nc) ? chtot[lane] : 0;
  int v = x;
#pragma unroll
  for (int off = 1; off < 64; off <<= 1) {
    int y = __shfl_up(v, off);
    bool sameseg = (lane >= off) && ((lane - off >= NCH_I) == (lane >= NCH_I));
    if (sameseg) v += y;
  }
  if (lane < nc) chtot[lane] = v - x;   // segmented exclusive prefix
}

// add chunk base to rp, zero cnt (reused as fill cursor), write rp[n] = NEDGE
__global__ __launch_bounds__(256) void scan3_kernel(int* rp_i, int* rp_u,
                                                    const int* __restrict__ chtot,
                                                    int* cnt_i, int* cnt_u) {
  int stride = gridDim.x * blockDim.x;
  const int total = NIs + NUs;
  for (int i = blockIdx.x * blockDim.x + threadIdx.x; i < total; i += stride) {
    if (i < NIs) {
      rp_i[i] += chtot[i / CHUNK];
      cnt_i[i] = 0;
    } else {
      int u = i - NIs;
      rp_u[u] += chtot[NCH_I + u / CHUNK];
      cnt_u[u] = 0;
    }
  }
  if (blockIdx.x == 0 && threadIdx.x == 0) {
    rp_i[NIs] = NEDGE;
    rp_u[NUs] = NEDGE;
  }
}

// scatter edges into CSR slots; combined (src, w_bits) int2 8B store halves
// the number of dirtied cache lines vs two 4B stores.
__global__ __launch_bounds__(256) void fill_kernel(const int* __restrict__ edge_u,
                                                   const int* __restrict__ edge_i,
                                                   const float* __restrict__ enorm,
                                                   const int* __restrict__ rp_i, int* cnt_i,
                                                   int2* __restrict__ pair_i,
                                                   const int* __restrict__ rp_u, int* cnt_u,
                                                   int2* __restrict__ pair_u) {
  int stride = gridDim.x * blockDim.x;
  for (int e = blockIdx.x * blockDim.x + threadIdx.x; e < NEDGE; e += stride) {
    int u = edge_u[e], it = edge_i[e];
    int wbits = __float_as_int(enorm[e]);
    int p = rp_i[it] + atomicAdd(&cnt_i[it], 1);
    pair_i[p] = make_int2(u, wbits);
    int q = rp_u[u] + atomicAdd(&cnt_u[u], 1);
    pair_u[q] = make_int2(it, wbits);
  }
}

// ---------------- relation-space precompute ----------------
// Rt[l][n][d] = sum_o RE[n][o] * (Wk[l][o][d] + Wk[l][o][D+d])
// cvec[l][n]  = sum_o RE[n][o] * Wkb[l][o]
__global__ __launch_bounds__(64) void rt_kernel(const float* __restrict__ RE,
                                                const float* __restrict__ Wkw,
                                                const float* __restrict__ Wkb,
                                                float* Rt, float* cvec) {
  int l = blockIdx.x >> 6;
  int n = blockIdx.x & 63;
  int d = threadIdx.x;
  const float* W  = Wkw + (size_t)l * DD * 2 * DD;
  const float* re = RE + n * DD;
  float acc = 0.f;
  for (int o = 0; o < DD; ++o) {
    float w = W[o * 2 * DD + d] + W[o * 2 * DD + DD + d];
    acc += re[o] * w;
  }
  Rt[(l * NRs + n) * DD + d] = acc;
  float p = re[d] * Wkb[l * DD + d];
  p = wave_sum_f(p);
  if (d == 0) cvec[l * NRs + n] = p;
}

// ---------------- KG attention (one wave per item) ----------------
__global__ __launch_bounds__(256) void attn_kernel(const float* __restrict__ EE,
                                                   const float* __restrict__ Rt_l,
                                                   const float* __restrict__ c_l,
                                                   const int* __restrict__ kg_ent,
                                                   const int* __restrict__ kg_rel,
                                                   const float* __restrict__ i_cur,
                                                   float* __restrict__ kg_item) {
  __shared__ float rt_s[NRs * DD];   // 16 KiB
  __shared__ float c_s[NRs];
  for (int m = threadIdx.x; m < NRs * DD; m += blockDim.x) rt_s[m] = Rt_l[m];
  for (int m = threadIdx.x; m < NRs; m += blockDim.x) c_s[m] = c_l[m];
  __syncthreads();
  int lane = threadIdx.x & 63;
  int wid = threadIdx.x >> 6;
  int wpg = gridDim.x * (blockDim.x >> 6);
  for (int i = blockIdx.x * (blockDim.x >> 6) + wid; i < NIs; i += wpg) {
    float icur = i_cur[i * DD + lane];
    int eidx = 0, ridx = 0;
    if (lane < KK) { eidx = kg_ent[i * KK + lane]; ridx = kg_rel[i * KK + lane]; }
    float vk[KK];
    float sc[KK];
#pragma unroll
    for (int k = 0; k < KK; ++k) {
      int ent = __shfl(eidx, k);
      int rel = __shfl(ridx, k);
      float v = EE[ent * DD + lane];
      vk[k] = v;
      float p = v * icur * rt_s[rel * DD + lane];
      p = wave_sum_f(p);
      float s = p + c_s[rel];
      sc[k] = (s >= 0.f) ? s : 0.2f * s;   // leaky_relu 0.2
    }
    float m = sc[0];
#pragma unroll
    for (int k = 1; k < KK; ++k) m = fmaxf(m, sc[k]);
    float ssum = 0.f;
#pragma unroll
    for (int k = 0; k < KK; ++k) { sc[k] = __expf(sc[k] - m); ssum += sc[k]; }
    float inv = 1.f / ssum;
    float kg = 0.f;
#pragma unroll
    for (int k = 0; k < KK; ++k) kg += sc[k] * inv * vk[k];
    kg_item[i * DD + lane] = kg;
  }
}

// ---------------- fused dual-direction CSR segment-sum ----------------
// rows [0, NIs):       aggi[r]  = sum_j w_i[j] * embU[src_i[j]]
// rows [NIs, NIs+NUs): unext[r] = sum_j w_u[j] * embI[src_u[j]]
//                      usum[r]  = (usum_init ? usum_init[r] : usum[r]) + unext[r]
// 16 lanes x float4 cover one 256B row; 4 lane-groups process 4 edges at once;
// two independent accumulator chains (8 edges in flight / wave).
__global__ __launch_bounds__(256) void agg2_kernel(
    const int* __restrict__ rp_i, const int2* __restrict__ pair_i,
    const float* __restrict__ embU, float* __restrict__ aggi,
    const int* __restrict__ rp_u, const int2* __restrict__ pair_u,
    const float* __restrict__ embI, float* __restrict__ unext,
    float* __restrict__ usum, const float* __restrict__ usum_init) {
  int lane = threadIdx.x & 63;
  int wid  = threadIdx.x >> 6;
  int sub  = lane & 15;   // which float4 of the row
  int grp  = lane >> 4;   // which of 4 concurrent edges
  int wpg  = gridDim.x * (blockDim.x >> 6);
  const int total = NIs + NUs;
  for (int row = blockIdx.x * (blockDim.x >> 6) + wid; row < total; row += wpg) {
    bool isU = row >= NIs;
    int r = isU ? (row - NIs) : row;
    const int*  rp = isU ? rp_u   : rp_i;
    const int2* pr = isU ? pair_u : pair_i;
    const float* emb = isU ? embI : embU;
    int s0 = rp[r], s1 = rp[r + 1];
    float ax0 = 0.f, ay0 = 0.f, az0 = 0.f, aw0 = 0.f;
    float ax1 = 0.f, ay1 = 0.f, az1 = 0.f, aw1 = 0.f;
    for (int base = s0; base < s1; base += 64) {
      int lim = s1 - base; if (lim > 64) lim = 64;
      int sj = 0; float wj = 0.f;
      if (lane < lim) {
        int2 pw = pr[base + lane];
        sj = pw.x; wj = __int_as_float(pw.y);
      }
      for (int j = 0; j < lim; j += 8) {
        int m0 = j + grp;        // <= 59
        int m1 = j + 4 + grp;    // <= 63
        int   a0 = __shfl(sj, m0); float q0 = __shfl(wj, m0);
        int   a1 = __shfl(sj, m1); float q1 = __shfl(wj, m1);
        float4 e0 = reinterpret_cast<const float4*>(emb + ((size_t)a0 << 6))[sub];
        float4 e1 = reinterpret_cast<const float4*>(emb + ((size_t)a1 << 6))[sub];
        ax0 += q0 * e0.x; ay0 += q0 * e0.y; az0 += q0 * e0.z; aw0 += q0 * e0.w;
        ax1 += q1 * e1.x; ay1 += q1 * e1.y; az1 += q1 * e1.z; aw1 += q1 * e1.w;
      }
    }
    float ax = ax0 + ax1, ay = ay0 + ay1, az = az0 + az1, aw = aw0 + aw1;
    ax += __shfl_xor(ax, 16); ay += __shfl_xor(ay, 16);
    az += __shfl_xor(az, 16); aw += __shfl_xor(aw, 16);
    ax += __shfl_xor(ax, 32); ay += __shfl_xor(ay, 32);
    az += __shfl_xor(az, 32); aw += __shfl_xor(aw, 32);
    if (lane < 16) {
      float4 o; o.x = ax; o.y = ay; o.z = az; o.w = aw;
      if (!isU) {
        reinterpret_cast<float4*>(aggi + ((size_t)r << 6))[sub] = o;
      } else {
        reinterpret_cast<float4*>(unext + ((size_t)r << 6))[sub] = o;
        float4 si;
        if (usum_init) si = reinterpret_cast<const float4*>(usum_init + ((size_t)r << 6))[sub];
        else           si = reinterpret_cast<float4*>(usum + ((size_t)r << 6))[sub];
        float4 s; s.x = si.x + ax; s.y = si.y + ay; s.z = si.z + az; s.w = si.w + aw;
        reinterpret_cast<float4*>(usum + ((size_t)r << 6))[sub] = s;
      }
    }
  }
}

// ---------------- gate + item update (one wave per item) ----------------
__global__ __launch_bounds__(256) void gate_kernel(const float* __restrict__ Wa,
                                                   const float* __restrict__ Wab,
                                                   const float* __restrict__ Wb,
                                                   const float* __restrict__ Wbb,
                                                   const float* __restrict__ kg_item,
                                                   const float* __restrict__ agg_i,
                                                   const float* __restrict__ i_sum_init,
                                                   float* __restrict__ i_next,
                                                   float* __restrict__ i_sum) {
  __shared__ float at[DD * 65];   // transposed, padded (conflict-free)
  __shared__ float bt[DD * 65];
  for (int m = threadIdx.x; m < DD * DD; m += blockDim.x) {
    int o = m >> 6, d = m & 63;
    at[d * 65 + o] = Wa[m];
    bt[d * 65 + o] = Wb[m];
  }
  __syncthreads();
  int lane = threadIdx.x & 63, wid = threadIdx.x >> 6;
  int wpg = gridDim.x * (blockDim.x >> 6);
  float wab = Wab[lane], wbb = Wbb[lane];
  for (int i = blockIdx.x * (blockDim.x >> 6) + wid; i < NIs; i += wpg) {
    float kg = kg_item[i * DD + lane];
    float ag = agg_i[i * DD + lane];
    float acca = 0.f, accb = 0.f;
#pragma unroll
    for (int d = 0; d < DD; ++d) {
      float kd = __shfl(kg, d);
      float ad = __shfl(ag, d);
      acca += kd * at[d * 65 + lane];
      accb += ad * bt[d * 65 + lane];
    }
    float g = 1.f / (1.f + __expf(-(acca + wab + accb + wbb)));
    float inew = g * kg + (1.f - g) * ag;
    i_next[i * DD + lane] = inew;
    if (i_sum_init) i_sum[i * DD + lane] = i_sum_init[i * DD + lane] + inew;
    else            i_sum[i * DD + lane] += inew;
  }
}

// ---------------- BPR loss ----------------
__global__ __launch_bounds__(256) void loss_kernel(const float* __restrict__ u_sum,
                                                   const float* __restrict__ i_sum,
                                                   const int* __restrict__ user,
                                                   const int* __restrict__ pos,
                                                   const int* __restrict__ neg,
                                                   float* acc) {
  int lane = threadIdx.x & 63, wid = threadIdx.x >> 6;
  int wpg = gridDim.x * (blockDim.x >> 6);
  float lacc = 0.f, l2acc = 0.f;
  for (int b = blockIdx.x * (blockDim.x >> 6) + wid; b < BB; b += wpg) {
    float u = u_sum[user[b] * DD + lane];
    float p = i_sum[pos[b] * DD + lane];
    float n = i_sum[neg[b] * DD + lane];
    float ps = wave_sum_f(u * p);
    float ns = wave_sum_f(u * n);
    float sq = wave_sum_f(u * u + p * p + n * n);
    if (lane == 0) {
      float x = ps - ns;
      float sig = 1.f / (1.f + expf(-x));
      lacc += logf(sig + 1e-10f);
      l2acc += sq;
    }
  }
  if (lane == 0) {
    atomicAdd(&acc[0], lacc);
    atomicAdd(&acc[1], l2acc);
  }
}

__global__ void final_kernel(const float* acc, float* out) {
  out[0] = -acc[0] / (float)BB + REGf * (acc[1] / (float)BB);
}

// ---------------- host ----------------

extern "C" void kernel_launch(void* const* d_in, const int* in_sizes, int n_in,
                              void* d_out, int out_size, void* d_ws, size_t ws_size,
                              hipStream_t stream) {
  const float* UE   = (const float*)d_in[0];
  const float* IE   = (const float*)d_in[1];
  const float* EE   = (const float*)d_in[2];
  const float* RE   = (const float*)d_in[3];
  const float* Wkw  = (const float*)d_in[4];
  const float* Wkb  = (const float*)d_in[5];
  const float* Waw  = (const float*)d_in[6];
  const float* Wab  = (const float*)d_in[7];
  const float* Wbw  = (const float*)d_in[8];
  const float* Wbb  = (const float*)d_in[9];
  const float* enorm = (const float*)d_in[10];
  const int* user   = (const int*)d_in[11];
  const int* pos    = (const int*)d_in[12];
  const int* neg    = (const int*)d_in[13];
  const int* edge_u = (const int*)d_in[14];
  const int* edge_i = (const int*)d_in[15];
  const int* kg_rel = (const int*)d_in[16];
  const int* kg_ent = (const int*)d_in[17];

  size_t off = 0;
  char* base = (char*)d_ws;
  auto take = [&](size_t bytes) -> void* {
    void* p = base + off;
    off += (bytes + 255) & ~(size_t)255;
    return p;
  };
  float* Rt     = (float*)take(LAYERS * NRs * DD * sizeof(float));
  float* cvec   = (float*)take(LAYERS * NRs * sizeof(float));
  float* acc    = (float*)take(8 * sizeof(float));
  int*   chtot  = (int*)take(64 * sizeof(int));
  int*   cnt_i  = (int*)take(NIs * sizeof(int));
  int*   cnt_u  = (int*)take(NUs * sizeof(int));
  int*   rp_i   = (int*)take((NIs + 1) * sizeof(int));
  int*   rp_u   = (int*)take((NUs + 1) * sizeof(int));
  int2*  pair_i = (int2*)take((size_t)NEDGE * sizeof(int2));
  int2*  pair_u = (int2*)take((size_t)NEDGE * sizeof(int2));
  float* kg     = (float*)take((size_t)NIs * DD * sizeof(float));
  float* aggi   = (float*)take((size_t)NIs * DD * sizeof(float));
  float* iA     = (float*)take((size_t)NIs * DD * sizeof(float));
  float* iB     = (float*)take((size_t)NIs * DD * sizeof(float));
  float* isum   = (float*)take((size_t)NIs * DD * sizeof(float));
  float* uA     = (float*)take((size_t)NUs * DD * sizeof(float));
  float* uB     = (float*)take((size_t)NUs * DD * sizeof(float));
  float* usum   = (float*)take((size_t)NUs * DD * sizeof(float));
  (void)ws_size; (void)in_sizes; (void)n_in; (void)out_size;

  hipMemsetAsync(cnt_i, 0, NIs * sizeof(int), stream);
  hipMemsetAsync(cnt_u, 0, NUs * sizeof(int), stream);
  hipMemsetAsync(acc, 0, 8 * sizeof(float), stream);

  hist_kernel<<<2048, 256, 0, stream>>>(edge_u, edge_i, cnt_u, cnt_i);
  scan1_kernel<<<NCH_I + NCH_U, 256, 0, stream>>>(cnt_i, cnt_u, rp_i, rp_u, chtot);
  scan2_kernel<<<1, 64, 0, stream>>>(chtot);
  scan3_kernel<<<256, 256, 0, stream>>>(rp_i, rp_u, chtot, cnt_i, cnt_u);
  fill_kernel<<<2048, 256, 0, stream>>>(edge_u, edge_i, enorm,
                                        rp_i, cnt_i, pair_i,
                                        rp_u, cnt_u, pair_u);
  rt_kernel<<<LAYERS * NRs, 64, 0, stream>>>(RE, Wkw, Wkb, Rt, cvec);

  const float* u_cur = UE;
  const float* i_cur = IE;
  float* unext[2] = {uA, uB};
  float* inext[2] = {iA, iB};
  for (int l = 0; l < LAYERS; ++l) {
    attn_kernel<<<2048, 256, 0, stream>>>(EE, Rt + l * NRs * DD, cvec + l * NRs,
                                          kg_ent, kg_rel, i_cur, kg);
    // fused: agg_i (items) + agg_u/u_next/u_sum (users) in one dispatch
    agg2_kernel<<<2048, 256, 0, stream>>>(rp_i, pair_i, u_cur, aggi,
                                          rp_u, pair_u, i_cur, unext[l],
                                          usum, (l == 0) ? UE : nullptr);
    // gate + item update + fused i_sum update
    gate_kernel<<<2048, 256, 0, stream>>>(Waw + (size_t)l * DD * DD, Wab + l * DD,
                                          Wbw + (size_t)l * DD * DD, Wbb + l * DD,
                                          kg, aggi, (l == 0) ? IE : nullptr,
                                          inext[l], isum);
    u_cur = unext[l];
    i_cur = inext[l];
  }

  loss_kernel<<<1024, 256, 0, stream>>>(usum, isum, user, pos, neg, acc);
  final_kernel<<<1, 1, 0, stream>>>(acc, (float*)d_out);
}

// Round 4
// 1141.057 us; speedup vs baseline: 1.1868x; 1.0750x over previous
//
#include <hip/hip_runtime.h>
#include <math.h>

constexpr int DD    = 64;        // embedding dim
constexpr int KK    = 16;        // kg neighbors per item
constexpr int NUs   = 100000;    // users
constexpr int NIs   = 50000;     // items
constexpr int NEs   = 200000;    // entities
constexpr int NRs   = 64;        // relations
constexpr int NEDGE = 2000000;   // edges (divisible by 4)
constexpr int LAYERS = 2;
constexpr int BB    = 4096;      // batch
constexpr float REGf = 1e-4f;

constexpr int CHUNK = 4096;                       // scan chunk per block
constexpr int NCH_I = (NIs + CHUNK - 1) / CHUNK;  // 13
constexpr int NCH_U = (NUs + CHUNK - 1) / CHUNK;  // 25

__device__ __forceinline__ float wave_sum_f(float x) {
#pragma unroll
  for (int off = 32; off > 0; off >>= 1) x += __shfl_xor(x, off);
  return x;
}

// ---------------- CSR build ----------------

// Blocked x4: each thread handles 4 consecutive edges with int4 loads.
// The atomic returns ARE the per-destination ordinals -> saved to ord[]
// (sequential int2 stores) so fill needs no atomics at all.
__global__ __launch_bounds__(256) void hist_kernel(const int* __restrict__ edge_u,
                                                   const int* __restrict__ edge_i,
                                                   int* cnt_u, int* cnt_i,
                                                   int2* __restrict__ ord) {
  int t = blockIdx.x * blockDim.x + threadIdx.x;
  int e0 = t * 4;
  if (e0 >= NEDGE) return;
  int4 u4 = *reinterpret_cast<const int4*>(edge_u + e0);
  int4 i4 = *reinterpret_cast<const int4*>(edge_i + e0);
  int oi0 = atomicAdd(&cnt_i[i4.x], 1);
  int ou0 = atomicAdd(&cnt_u[u4.x], 1);
  int oi1 = atomicAdd(&cnt_i[i4.y], 1);
  int ou1 = atomicAdd(&cnt_u[u4.y], 1);
  int oi2 = atomicAdd(&cnt_i[i4.z], 1);
  int ou2 = atomicAdd(&cnt_u[u4.z], 1);
  int oi3 = atomicAdd(&cnt_i[i4.w], 1);
  int ou3 = atomicAdd(&cnt_u[u4.w], 1);
  int4* op = reinterpret_cast<int4*>(ord + e0);
  op[0] = make_int4(oi0, ou0, oi1, ou1);
  op[1] = make_int4(oi2, ou2, oi3, ou3);
}

// chunk-local exclusive scan: block cb handles 4096 elements of cnt_i (cb < NCH_I)
// or cnt_u; writes within-chunk exclusive prefix into rp, chunk total into chtot.
__global__ __launch_bounds__(256) void scan1_kernel(const int* __restrict__ cnt_i,
                                                    const int* __restrict__ cnt_u,
                                                    int* rp_i, int* rp_u, int* chtot) {
  int cb = blockIdx.x;
  const int* cnt; int* rp; int n; int base;
  if (cb < NCH_I) { cnt = cnt_i; rp = rp_i; n = NIs; base = cb * CHUNK; }
  else            { cnt = cnt_u; rp = rp_u; n = NUs; base = (cb - NCH_I) * CHUNK; }
  int tid = threadIdx.x;
  int start = base + tid * 16;
  int vals[16];
  int s = 0;
#pragma unroll
  for (int j = 0; j < 16; ++j) {
    int idx = start + j;
    int v = (idx < n) ? cnt[idx] : 0;
    vals[j] = s;              // exclusive within-thread
    s += v;
  }
  int lane = tid & 63, wid = tid >> 6;
  int v = s;
#pragma unroll
  for (int off = 1; off < 64; off <<= 1) {
    int y = __shfl_up(v, off);
    if (lane >= off) v += y;
  }
  __shared__ int wt[4];
  if (lane == 63) wt[wid] = v;
  __syncthreads();
  int woff = 0;
#pragma unroll
  for (int w = 0; w < 4; ++w) if (w < wid) woff += wt[w];
  int texcl = woff + v - s;   // exclusive prefix of this thread's total within chunk
#pragma unroll
  for (int j = 0; j < 16; ++j) {
    int idx = start + j;
    if (idx < n) rp[idx] = texcl + vals[j];
  }
  if (tid == 255) chtot[cb] = woff + v;   // chunk total
}

// one wave: segmented exclusive scan of the 38 chunk totals (items | users)
__global__ __launch_bounds__(64) void scan2_kernel(int* chtot) {
  int lane = threadIdx.x;
  const int nc = NCH_I + NCH_U;
  int x = (lane < nc) ? chtot[lane] : 0;
  int v = x;
#pragma unroll
  for (int off = 1; off < 64; off <<= 1) {
    int y = __shfl_up(v, off);
    bool sameseg = (lane >= off) && ((lane - off >= NCH_I) == (lane >= NCH_I));
    if (sameseg) v += y;
  }
  if (lane < nc) chtot[lane] = v - x;   // segmented exclusive prefix
}

// add chunk base to rp, write rp[n] = NEDGE
__global__ __launch_bounds__(256) void scan3_kernel(int* rp_i, int* rp_u,
                                                    const int* __restrict__ chtot) {
  int stride = gridDim.x * blockDim.x;
  const int total = NIs + NUs;
  for (int i = blockIdx.x * blockDim.x + threadIdx.x; i < total; i += stride) {
    if (i < NIs) {
      rp_i[i] += chtot[i / CHUNK];
    } else {
      int u = i - NIs;
      rp_u[u] += chtot[NCH_I + u / CHUNK];
    }
  }
  if (blockIdx.x == 0 && threadIdx.x == 0) {
    rp_i[NIs] = NEDGE;
    rp_u[NUs] = NEDGE;
  }
}

// Atomic-free scatter: slot = rp[dst] + precomputed ordinal. Blocked x4 with
// vector loads; 8 independent gather+store pairs in flight per thread.
__global__ __launch_bounds__(256) void fill_kernel(const int* __restrict__ edge_u,
                                                   const int* __restrict__ edge_i,
                                                   const float* __restrict__ enorm,
                                                   const int2* __restrict__ ord,
                                                   const int* __restrict__ rp_i,
                                                   int2* __restrict__ pair_i,
                                                   const int* __restrict__ rp_u,
                                                   int2* __restrict__ pair_u) {
  int t = blockIdx.x * blockDim.x + threadIdx.x;
  int e0 = t * 4;
  if (e0 >= NEDGE) return;
  int4 u4 = *reinterpret_cast<const int4*>(edge_u + e0);
  int4 i4 = *reinterpret_cast<const int4*>(edge_i + e0);
  float4 w4 = *reinterpret_cast<const float4*>(enorm + e0);
  const int4* op = reinterpret_cast<const int4*>(ord + e0);
  int4 oa = op[0];   // (oi0, ou0, oi1, ou1)
  int4 ob = op[1];   // (oi2, ou2, oi3, ou3)
  int bi0 = rp_i[i4.x], bu0 = rp_u[u4.x];
  int bi1 = rp_i[i4.y], bu1 = rp_u[u4.y];
  int bi2 = rp_i[i4.z], bu2 = rp_u[u4.z];
  int bi3 = rp_i[i4.w], bu3 = rp_u[u4.w];
  pair_i[bi0 + oa.x] = make_int2(u4.x, __float_as_int(w4.x));
  pair_u[bu0 + oa.y] = make_int2(i4.x, __float_as_int(w4.x));
  pair_i[bi1 + oa.z] = make_int2(u4.y, __float_as_int(w4.y));
  pair_u[bu1 + oa.w] = make_int2(i4.y, __float_as_int(w4.y));
  pair_i[bi2 + ob.x] = make_int2(u4.z, __float_as_int(w4.z));
  pair_u[bu2 + ob.y] = make_int2(i4.z, __float_as_int(w4.z));
  pair_i[bi3 + ob.z] = make_int2(u4.w, __float_as_int(w4.w));
  pair_u[bu3 + ob.w] = make_int2(i4.w, __float_as_int(w4.w));
}

// ---------------- relation-space precompute ----------------
// Rt[l][n][d] = sum_o RE[n][o] * (Wk[l][o][d] + Wk[l][o][D+d])
// cvec[l][n]  = sum_o RE[n][o] * Wkb[l][o]
__global__ __launch_bounds__(64) void rt_kernel(const float* __restrict__ RE,
                                                const float* __restrict__ Wkw,
                                                const float* __restrict__ Wkb,
                                                float* Rt, float* cvec) {
  int l = blockIdx.x >> 6;
  int n = blockIdx.x & 63;
  int d = threadIdx.x;
  const float* W  = Wkw + (size_t)l * DD * 2 * DD;
  const float* re = RE + n * DD;
  float acc = 0.f;
  for (int o = 0; o < DD; ++o) {
    float w = W[o * 2 * DD + d] + W[o * 2 * DD + DD + d];
    acc += re[o] * w;
  }
  Rt[(l * NRs + n) * DD + d] = acc;
  float p = re[d] * Wkb[l * DD + d];
  p = wave_sum_f(p);
  if (d == 0) cvec[l * NRs + n] = p;
}

// ---------------- KG attention (one wave per item) ----------------
__global__ __launch_bounds__(256) void attn_kernel(const float* __restrict__ EE,
                                                   const float* __restrict__ Rt_l,
                                                   const float* __restrict__ c_l,
                                                   const int* __restrict__ kg_ent,
                                                   const int* __restrict__ kg_rel,
                                                   const float* __restrict__ i_cur,
                                                   float* __restrict__ kg_item) {
  __shared__ float rt_s[NRs * DD];   // 16 KiB
  __shared__ float c_s[NRs];
  for (int m = threadIdx.x; m < NRs * DD; m += blockDim.x) rt_s[m] = Rt_l[m];
  for (int m = threadIdx.x; m < NRs; m += blockDim.x) c_s[m] = c_l[m];
  __syncthreads();
  int lane = threadIdx.x & 63;
  int wid = threadIdx.x >> 6;
  int wpg = gridDim.x * (blockDim.x >> 6);
  for (int i = blockIdx.x * (blockDim.x >> 6) + wid; i < NIs; i += wpg) {
    float icur = i_cur[i * DD + lane];
    int eidx = 0, ridx = 0;
    if (lane < KK) { eidx = kg_ent[i * KK + lane]; ridx = kg_rel[i * KK + lane]; }
    float vk[KK];
    float sc[KK];
#pragma unroll
    for (int k = 0; k < KK; ++k) {
      int ent = __shfl(eidx, k);
      int rel = __shfl(ridx, k);
      float v = EE[ent * DD + lane];
      vk[k] = v;
      float p = v * icur * rt_s[rel * DD + lane];
      p = wave_sum_f(p);
      float s = p + c_s[rel];
      sc[k] = (s >= 0.f) ? s : 0.2f * s;   // leaky_relu 0.2
    }
    float m = sc[0];
#pragma unroll
    for (int k = 1; k < KK; ++k) m = fmaxf(m, sc[k]);
    float ssum = 0.f;
#pragma unroll
    for (int k = 0; k < KK; ++k) { sc[k] = __expf(sc[k] - m); ssum += sc[k]; }
    float inv = 1.f / ssum;
    float kg = 0.f;
#pragma unroll
    for (int k = 0; k < KK; ++k) kg += sc[k] * inv * vk[k];
    kg_item[i * DD + lane] = kg;
  }
}

// ---------------- fused dual-direction CSR segment-sum ----------------
// rows [0, NIs):       aggi[r]  = sum_j w_i[j] * embU[src_i[j]]
// rows [NIs, NIs+NUs): unext[r] = sum_j w_u[j] * embI[src_u[j]]
//                      usum[r]  = (usum_init ? usum_init[r] : usum[r]) + unext[r]
// 16 lanes x float4 cover one 256B row; 4 lane-groups process 4 edges at once;
// two independent accumulator chains (8 edges in flight / wave).
__global__ __launch_bounds__(256) void agg2_kernel(
    const int* __restrict__ rp_i, const int2* __restrict__ pair_i,
    const float* __restrict__ embU, float* __restrict__ aggi,
    const int* __restrict__ rp_u, const int2* __restrict__ pair_u,
    const float* __restrict__ embI, float* __restrict__ unext,
    float* __restrict__ usum, const float* __restrict__ usum_init) {
  int lane = threadIdx.x & 63;
  int wid  = threadIdx.x >> 6;
  int sub  = lane & 15;   // which float4 of the row
  int grp  = lane >> 4;   // which of 4 concurrent edges
  int wpg  = gridDim.x * (blockDim.x >> 6);
  const int total = NIs + NUs;
  for (int row = blockIdx.x * (blockDim.x >> 6) + wid; row < total; row += wpg) {
    bool isU = row >= NIs;
    int r = isU ? (row - NIs) : row;
    const int*  rp = isU ? rp_u   : rp_i;
    const int2* pr = isU ? pair_u : pair_i;
    const float* emb = isU ? embI : embU;
    int s0 = rp[r], s1 = rp[r + 1];
    float ax0 = 0.f, ay0 = 0.f, az0 = 0.f, aw0 = 0.f;
    float ax1 = 0.f, ay1 = 0.f, az1 = 0.f, aw1 = 0.f;
    for (int base = s0; base < s1; base += 64) {
      int lim = s1 - base; if (lim > 64) lim = 64;
      int sj = 0; float wj = 0.f;
      if (lane < lim) {
        int2 pw = pr[base + lane];
        sj = pw.x; wj = __int_as_float(pw.y);
      }
      for (int j = 0; j < lim; j += 8) {
        int m0 = j + grp;        // <= 59
        int m1 = j + 4 + grp;    // <= 63
        int   a0 = __shfl(sj, m0); float q0 = __shfl(wj, m0);
        int   a1 = __shfl(sj, m1); float q1 = __shfl(wj, m1);
        float4 e0 = reinterpret_cast<const float4*>(emb + ((size_t)a0 << 6))[sub];
        float4 e1 = reinterpret_cast<const float4*>(emb + ((size_t)a1 << 6))[sub];
        ax0 += q0 * e0.x; ay0 += q0 * e0.y; az0 += q0 * e0.z; aw0 += q0 * e0.w;
        ax1 += q1 * e1.x; ay1 += q1 * e1.y; az1 += q1 * e1.z; aw1 += q1 * e1.w;
      }
    }
    float ax = ax0 + ax1, ay = ay0 + ay1, az = az0 + az1, aw = aw0 + aw1;
    ax += __shfl_xor(ax, 16); ay += __shfl_xor(ay, 16);
    az += __shfl_xor(az, 16); aw += __shfl_xor(aw, 16);
    ax += __shfl_xor(ax, 32); ay += __shfl_xor(ay, 32);
    az += __shfl_xor(az, 32); aw += __shfl_xor(aw, 32);
    if (lane < 16) {
      float4 o; o.x = ax; o.y = ay; o.z = az; o.w = aw;
      if (!isU) {
        reinterpret_cast<float4*>(aggi + ((size_t)r << 6))[sub] = o;
      } else {
        reinterpret_cast<float4*>(unext + ((size_t)r << 6))[sub] = o;
        float4 si;
        if (usum_init) si = reinterpret_cast<const float4*>(usum_init + ((size_t)r << 6))[sub];
        else           si = reinterpret_cast<float4*>(usum + ((size_t)r << 6))[sub];
        float4 s; s.x = si.x + ax; s.y = si.y + ay; s.z = si.z + az; s.w = si.w + aw;
        reinterpret_cast<float4*>(usum + ((size_t)r << 6))[sub] = s;
      }
    }
  }
}

// ---------------- gate + item update (one wave per item) ----------------
__global__ __launch_bounds__(256) void gate_kernel(const float* __restrict__ Wa,
                                                   const float* __restrict__ Wab,
                                                   const float* __restrict__ Wb,
                                                   const float* __restrict__ Wbb,
                                                   const float* __restrict__ kg_item,
                                                   const float* __restrict__ agg_i,
                                                   const float* __restrict__ i_sum_init,
                                                   float* __restrict__ i_next,
                                                   float* __restrict__ i_sum) {
  __shared__ float at[DD * 65];   // transposed, padded (conflict-free)
  __shared__ float bt[DD * 65];
  for (int m = threadIdx.x; m < DD * DD; m += blockDim.x) {
    int o = m >> 6, d = m & 63;
    at[d * 65 + o] = Wa[m];
    bt[d * 65 + o] = Wb[m];
  }
  __syncthreads();
  int lane = threadIdx.x & 63, wid = threadIdx.x >> 6;
  int wpg = gridDim.x * (blockDim.x >> 6);
  float wab = Wab[lane], wbb = Wbb[lane];
  for (int i = blockIdx.x * (blockDim.x >> 6) + wid; i < NIs; i += wpg) {
    float kg = kg_item[i * DD + lane];
    float ag = agg_i[i * DD + lane];
    float acca = 0.f, accb = 0.f;
#pragma unroll
    for (int d = 0; d < DD; ++d) {
      float kd = __shfl(kg, d);
      float ad = __shfl(ag, d);
      acca += kd * at[d * 65 + lane];
      accb += ad * bt[d * 65 + lane];
    }
    float g = 1.f / (1.f + __expf(-(acca + wab + accb + wbb)));
    float inew = g * kg + (1.f - g) * ag;
    i_next[i * DD + lane] = inew;
    if (i_sum_init) i_sum[i * DD + lane] = i_sum_init[i * DD + lane] + inew;
    else            i_sum[i * DD + lane] += inew;
  }
}

// ---------------- BPR loss ----------------
__global__ __launch_bounds__(256) void loss_kernel(const float* __restrict__ u_sum,
                                                   const float* __restrict__ i_sum,
                                                   const int* __restrict__ user,
                                                   const int* __restrict__ pos,
                                                   const int* __restrict__ neg,
                                                   float* acc) {
  int lane = threadIdx.x & 63, wid = threadIdx.x >> 6;
  int wpg = gridDim.x * (blockDim.x >> 6);
  float lacc = 0.f, l2acc = 0.f;
  for (int b = blockIdx.x * (blockDim.x >> 6) + wid; b < BB; b += wpg) {
    float u = u_sum[user[b] * DD + lane];
    float p = i_sum[pos[b] * DD + lane];
    float n = i_sum[neg[b] * DD + lane];
    float ps = wave_sum_f(u * p);
    float ns = wave_sum_f(u * n);
    float sq = wave_sum_f(u * u + p * p + n * n);
    if (lane == 0) {
      float x = ps - ns;
      float sig = 1.f / (1.f + expf(-x));
      lacc += logf(sig + 1e-10f);
      l2acc += sq;
    }
  }
  if (lane == 0) {
    atomicAdd(&acc[0], lacc);
    atomicAdd(&acc[1], l2acc);
  }
}

__global__ void final_kernel(const float* acc, float* out) {
  out[0] = -acc[0] / (float)BB + REGf * (acc[1] / (float)BB);
}

// ---------------- host ----------------

extern "C" void kernel_launch(void* const* d_in, const int* in_sizes, int n_in,
                              void* d_out, int out_size, void* d_ws, size_t ws_size,
                              hipStream_t stream) {
  const float* UE   = (const float*)d_in[0];
  const float* IE   = (const float*)d_in[1];
  const float* EE   = (const float*)d_in[2];
  const float* RE   = (const float*)d_in[3];
  const float* Wkw  = (const float*)d_in[4];
  const float* Wkb  = (const float*)d_in[5];
  const float* Waw  = (const float*)d_in[6];
  const float* Wab  = (const float*)d_in[7];
  const float* Wbw  = (const float*)d_in[8];
  const float* Wbb  = (const float*)d_in[9];
  const float* enorm = (const float*)d_in[10];
  const int* user   = (const int*)d_in[11];
  const int* pos    = (const int*)d_in[12];
  const int* neg    = (const int*)d_in[13];
  const int* edge_u = (const int*)d_in[14];
  const int* edge_i = (const int*)d_in[15];
  const int* kg_rel = (const int*)d_in[16];
  const int* kg_ent = (const int*)d_in[17];

  size_t off = 0;
  char* base = (char*)d_ws;
  auto take = [&](size_t bytes) -> void* {
    void* p = base + off;
    off += (bytes + 255) & ~(size_t)255;
    return p;
  };
  float* Rt     = (float*)take(LAYERS * NRs * DD * sizeof(float));
  float* cvec   = (float*)take(LAYERS * NRs * sizeof(float));
  float* acc    = (float*)take(8 * sizeof(float));
  int*   chtot  = (int*)take(64 * sizeof(int));
  int*   cnt_i  = (int*)take(NIs * sizeof(int));
  int*   cnt_u  = (int*)take(NUs * sizeof(int));
  int*   rp_i   = (int*)take((NIs + 1) * sizeof(int));
  int*   rp_u   = (int*)take((NUs + 1) * sizeof(int));
  int2*  ord    = (int2*)take((size_t)NEDGE * sizeof(int2));
  int2*  pair_i = (int2*)take((size_t)NEDGE * sizeof(int2));
  int2*  pair_u = (int2*)take((size_t)NEDGE * sizeof(int2));
  float* kg     = (float*)take((size_t)NIs * DD * sizeof(float));
  float* aggi   = (float*)take((size_t)NIs * DD * sizeof(float));
  float* iA     = (float*)take((size_t)NIs * DD * sizeof(float));
  float* iB     = (float*)take((size_t)NIs * DD * sizeof(float));
  float* isum   = (float*)take((size_t)NIs * DD * sizeof(float));
  float* uA     = (float*)take((size_t)NUs * DD * sizeof(float));
  float* uB     = (float*)take((size_t)NUs * DD * sizeof(float));
  float* usum   = (float*)take((size_t)NUs * DD * sizeof(float));
  (void)ws_size; (void)in_sizes; (void)n_in; (void)out_size;

  hipMemsetAsync(cnt_i, 0, NIs * sizeof(int), stream);
  hipMemsetAsync(cnt_u, 0, NUs * sizeof(int), stream);
  hipMemsetAsync(acc, 0, 8 * sizeof(float), stream);

  const int histGrid = (NEDGE / 4 + 255) / 256;   // 1954
  hist_kernel<<<histGrid, 256, 0, stream>>>(edge_u, edge_i, cnt_u, cnt_i, ord);
  scan1_kernel<<<NCH_I + NCH_U, 256, 0, stream>>>(cnt_i, cnt_u, rp_i, rp_u, chtot);
  scan2_kernel<<<1, 64, 0, stream>>>(chtot);
  scan3_kernel<<<256, 256, 0, stream>>>(rp_i, rp_u, chtot);
  fill_kernel<<<histGrid, 256, 0, stream>>>(edge_u, edge_i, enorm, ord,
                                            rp_i, pair_i, rp_u, pair_u);
  rt_kernel<<<LAYERS * NRs, 64, 0, stream>>>(RE, Wkw, Wkb, Rt, cvec);

  const float* u_cur = UE;
  const float* i_cur = IE;
  float* unext[2] = {uA, uB};
  float* inext[2] = {iA, iB};
  for (int l = 0; l < LAYERS; ++l) {
    attn_kernel<<<2048, 256, 0, stream>>>(EE, Rt + l * NRs * DD, cvec + l * NRs,
                                          kg_ent, kg_rel, i_cur, kg);
    // fused: agg_i (items) + agg_u/u_next/u_sum (users) in one dispatch
    agg2_kernel<<<2048, 256, 0, stream>>>(rp_i, pair_i, u_cur, aggi,
                                          rp_u, pair_u, i_cur, unext[l],
                                          usum, (l == 0) ? UE : nullptr);
    // gate + item update + fused i_sum update
    gate_kernel<<<2048, 256, 0, stream>>>(Waw + (size_t)l * DD * DD, Wab + l * DD,
                                          Wbw + (size_t)l * DD * DD, Wbb + l * DD,
                                          kg, aggi, (l == 0) ? IE : nullptr,
                                          inext[l], isum);
    u_cur = unext[l];
    i_cur = inext[l];
  }

  loss_kernel<<<1024, 256, 0, stream>>>(usum, isum, user, pos, neg, acc);
  final_kernel<<<1, 1, 0, stream>>>(acc, (float*)d_out);
}

// Round 5
// 1026.937 us; speedup vs baseline: 1.3187x; 1.1111x over previous
//
#include <hip/hip_runtime.h>
#include <math.h>

constexpr int DD    = 64;        // embedding dim
constexpr int KK    = 16;        // kg neighbors per item
constexpr int NUs   = 100000;    // users
constexpr int NIs   = 50000;     // items
constexpr int NEs   = 200000;    // entities
constexpr int NRs   = 64;        // relations
constexpr int NEDGE = 2000000;   // edges
constexpr int LAYERS = 2;
constexpr int BB    = 4096;      // batch
constexpr float REGf = 1e-4f;

// bucket CSR build
constexpr int SUBB  = 256;                         // destinations per bucket
constexpr int NB_I  = (NIs + SUBB - 1) / SUBB;     // 196
constexpr int NB_U  = (NUs + SUBB - 1) / SUBB;     // 391
constexpr int NBT   = NB_I + NB_U;                 // 587
constexpr int CH    = 8192;                        // edges per block chunk
constexpr int NCHK  = (NEDGE + CH - 1) / CH;       // 245

__device__ __forceinline__ float wave_sum_f(float x) {
#pragma unroll
  for (int off = 32; off > 0; off >>= 1) x += __shfl_xor(x, off);
  return x;
}

// ---------------- CSR build: two-level bucket counting sort ----------------

// A) global bucket histogram via per-block LDS hist (one global atomic per
//    (block,bucket) instead of per edge).
__global__ __launch_bounds__(256) void bhist_kernel(const int* __restrict__ edge_u,
                                                    const int* __restrict__ edge_i,
                                                    int* __restrict__ gbkt) {
  __shared__ int lcnt[NBT];
  for (int b = threadIdx.x; b < NBT; b += 256) lcnt[b] = 0;
  __syncthreads();
  int base = blockIdx.x * CH;
  for (int k = threadIdx.x; k < CH; k += 256) {
    int e = base + k;
    if (e < NEDGE) {
      atomicAdd(&lcnt[edge_i[e] >> 8], 1);
      atomicAdd(&lcnt[NB_I + (edge_u[e] >> 8)], 1);
    }
  }
  __syncthreads();
  for (int b = threadIdx.x; b < NBT; b += 256) {
    int c = lcnt[b];
    if (c) atomicAdd(&gbkt[b], c);
  }
}

// B) segmented exclusive scan of the 587 bucket totals (items | users);
//    writes bucket bases and initializes scatter cursors; writes rp[n].
__global__ __launch_bounds__(1024) void bscan_kernel(const int* __restrict__ gbkt,
                                                     int* __restrict__ bktbase,
                                                     int* __restrict__ bktcur,
                                                     int* rp_i, int* rp_u) {
  __shared__ int sv[1024];
  int tid = threadIdx.x;
  int x = (tid < NBT) ? gbkt[tid] : 0;
  bool segU = (tid >= NB_I);
  int v = x;
  sv[tid] = v;
  __syncthreads();
  for (int off = 1; off < 1024; off <<= 1) {
    int y = 0;
    if (tid >= off) {
      int o = tid - off;
      if ((o >= NB_I) == segU) y = sv[o];
    }
    __syncthreads();
    v += y;
    sv[tid] = v;
    __syncthreads();
  }
  if (tid < NBT) {
    int ex = v - x;
    bktbase[tid] = ex;
    bktcur[tid] = ex;
  }
  if (tid == 0) { rp_i[NIs] = NEDGE; rp_u[NUs] = NEDGE; }
}

// C) scatter edges bucket-grouped. Per-block LDS hist -> one global atomic per
//    (block,bucket) reserves a contiguous run -> writes are clustered runs
//    (~112B) inside each bucket region (L2-line coalesced).
//    Key packs (dest & 255) << 20 | src  (src < 2^17 fits in 20 bits).
__global__ __launch_bounds__(256) void bscatter_kernel(const int* __restrict__ edge_u,
                                                       const int* __restrict__ edge_i,
                                                       const float* __restrict__ enorm,
                                                       int* __restrict__ bktcur,
                                                       int2* __restrict__ tmp_i,
                                                       int2* __restrict__ tmp_u) {
  __shared__ int lcnt[NBT];
  __shared__ int lbase[NBT];
  for (int b = threadIdx.x; b < NBT; b += 256) lcnt[b] = 0;
  __syncthreads();
  int base = blockIdx.x * CH;
  for (int k = threadIdx.x; k < CH; k += 256) {
    int e = base + k;
    if (e < NEDGE) {
      atomicAdd(&lcnt[edge_i[e] >> 8], 1);
      atomicAdd(&lcnt[NB_I + (edge_u[e] >> 8)], 1);
    }
  }
  __syncthreads();
  for (int b = threadIdx.x; b < NBT; b += 256) {
    int c = lcnt[b];
    lbase[b] = c ? atomicAdd(&bktcur[b], c) : 0;
    lcnt[b] = 0;
  }
  __syncthreads();
  for (int k = threadIdx.x; k < CH; k += 256) {
    int e = base + k;
    if (e < NEDGE) {
      int it = edge_i[e], u = edge_u[e];
      int wb = __float_as_int(enorm[e]);
      int bi = it >> 8;
      int p = lbase[bi] + atomicAdd(&lcnt[bi], 1);
      tmp_i[p] = make_int2(((it & 255) << 20) | u, wb);
      int bu = NB_I + (u >> 8);
      int q = lbase[bu] + atomicAdd(&lcnt[bu], 1);
      tmp_u[q] = make_int2(((u & 255) << 20) | it, wb);
    }
  }
}

// D) per-bucket counting sort into final CSR order + rp write. All random
//    work in LDS; global writes confined to this bucket's contiguous region.
__global__ __launch_bounds__(256) void bsort_kernel(const int* __restrict__ gbkt,
                                                    const int* __restrict__ bktbase,
                                                    const int2* __restrict__ tmp_i,
                                                    const int2* __restrict__ tmp_u,
                                                    int2* __restrict__ pair_i,
                                                    int2* __restrict__ pair_u,
                                                    int* __restrict__ rp_i,
                                                    int* __restrict__ rp_u) {
  int b = blockIdx.x;
  bool isI = (b < NB_I);
  const int2* tmp = isI ? tmp_i : tmp_u;
  int2* po = isI ? pair_i : pair_u;
  int* rp = isI ? rp_i : rp_u;
  int ndst = isI ? NIs : NUs;
  int localb = isI ? b : b - NB_I;
  int start = bktbase[b];
  int size = gbkt[b];
  __shared__ int dcnt[256];
  __shared__ int dpos[256];
  __shared__ int wt[4];
  int tid = threadIdx.x;
  dcnt[tid] = 0;
  __syncthreads();
  for (int k = tid; k < size; k += 256) atomicAdd(&dcnt[tmp[start + k].x >> 20], 1);
  __syncthreads();
  int c = dcnt[tid];
  int lane = tid & 63, wid = tid >> 6;
  int v = c;
#pragma unroll
  for (int off = 1; off < 64; off <<= 1) {
    int y = __shfl_up(v, off);
    if (lane >= off) v += y;
  }
  if (lane == 63) wt[wid] = v;
  __syncthreads();
  int woff = 0;
#pragma unroll
  for (int w = 0; w < 4; ++w)
    if (w < wid) woff += wt[w];
  int excl = woff + v - c;
  dpos[tid] = excl;
  int idx = localb * 256 + tid;
  if (idx < ndst) rp[idx] = start + excl;
  dcnt[tid] = 0;
  __syncthreads();
  for (int k = tid; k < size; k += 256) {
    int2 pw = tmp[start + k];
    int sub = pw.x >> 20;
    int j = dpos[sub] + atomicAdd(&dcnt[sub], 1);
    po[start + j] = make_int2(pw.x & 0xFFFFF, pw.y);
  }
}

// ---------------- relation-space precompute ----------------
// Rt[l][n][d] = sum_o RE[n][o] * (Wk[l][o][d] + Wk[l][o][D+d])
// cvec[l][n]  = sum_o RE[n][o] * Wkb[l][o]
__global__ __launch_bounds__(64) void rt_kernel(const float* __restrict__ RE,
                                                const float* __restrict__ Wkw,
                                                const float* __restrict__ Wkb,
                                                float* Rt, float* cvec) {
  int l = blockIdx.x >> 6;
  int n = blockIdx.x & 63;
  int d = threadIdx.x;
  const float* W  = Wkw + (size_t)l * DD * 2 * DD;
  const float* re = RE + n * DD;
  float acc = 0.f;
  for (int o = 0; o < DD; ++o) {
    float w = W[o * 2 * DD + d] + W[o * 2 * DD + DD + d];
    acc += re[o] * w;
  }
  Rt[(l * NRs + n) * DD + d] = acc;
  float p = re[d] * Wkb[l * DD + d];
  p = wave_sum_f(p);
  if (d == 0) cvec[l * NRs + n] = p;
}

// ---------------- KG attention (one wave per item) ----------------
__global__ __launch_bounds__(256) void attn_kernel(const float* __restrict__ EE,
                                                   const float* __restrict__ Rt_l,
                                                   const float* __restrict__ c_l,
                                                   const int* __restrict__ kg_ent,
                                                   const int* __restrict__ kg_rel,
                                                   const float* __restrict__ i_cur,
                                                   float* __restrict__ kg_item) {
  __shared__ float rt_s[NRs * DD];   // 16 KiB
  __shared__ float c_s[NRs];
  for (int m = threadIdx.x; m < NRs * DD; m += blockDim.x) rt_s[m] = Rt_l[m];
  for (int m = threadIdx.x; m < NRs; m += blockDim.x) c_s[m] = c_l[m];
  __syncthreads();
  int lane = threadIdx.x & 63;
  int wid = threadIdx.x >> 6;
  int wpg = gridDim.x * (blockDim.x >> 6);
  for (int i = blockIdx.x * (blockDim.x >> 6) + wid; i < NIs; i += wpg) {
    float icur = i_cur[i * DD + lane];
    int eidx = 0, ridx = 0;
    if (lane < KK) { eidx = kg_ent[i * KK + lane]; ridx = kg_rel[i * KK + lane]; }
    float vk[KK];
    float sc[KK];
#pragma unroll
    for (int k = 0; k < KK; ++k) {
      int ent = __shfl(eidx, k);
      int rel = __shfl(ridx, k);
      float v = EE[ent * DD + lane];
      vk[k] = v;
      float p = v * icur * rt_s[rel * DD + lane];
      p = wave_sum_f(p);
      float s = p + c_s[rel];
      sc[k] = (s >= 0.f) ? s : 0.2f * s;   // leaky_relu 0.2
    }
    float m = sc[0];
#pragma unroll
    for (int k = 1; k < KK; ++k) m = fmaxf(m, sc[k]);
    float ssum = 0.f;
#pragma unroll
    for (int k = 0; k < KK; ++k) { sc[k] = __expf(sc[k] - m); ssum += sc[k]; }
    float inv = 1.f / ssum;
    float kg = 0.f;
#pragma unroll
    for (int k = 0; k < KK; ++k) kg += sc[k] * inv * vk[k];
    kg_item[i * DD + lane] = kg;
  }
}

// ---------------- fused dual-direction CSR segment-sum ----------------
// rows [0, NIs):       aggi[r]  = sum_j w_i[j] * embU[src_i[j]]
// rows [NIs, NIs+NUs): unext[r] = sum_j w_u[j] * embI[src_u[j]]
//                      usum[r]  = (usum_init ? usum_init[r] : usum[r]) + unext[r]
// 16 lanes x float4 cover one 256B row; 4 lane-groups process 4 edges at once;
// two independent accumulator chains (8 edges in flight / wave).
__global__ __launch_bounds__(256) void agg2_kernel(
    const int* __restrict__ rp_i, const int2* __restrict__ pair_i,
    const float* __restrict__ embU, float* __restrict__ aggi,
    const int* __restrict__ rp_u, const int2* __restrict__ pair_u,
    const float* __restrict__ embI, float* __restrict__ unext,
    float* __restrict__ usum, const float* __restrict__ usum_init) {
  int lane = threadIdx.x & 63;
  int wid  = threadIdx.x >> 6;
  int sub  = lane & 15;   // which float4 of the row
  int grp  = lane >> 4;   // which of 4 concurrent edges
  int wpg  = gridDim.x * (blockDim.x >> 6);
  const int total = NIs + NUs;
  for (int row = blockIdx.x * (blockDim.x >> 6) + wid; row < total; row += wpg) {
    bool isU = row >= NIs;
    int r = isU ? (row - NIs) : row;
    const int*  rp = isU ? rp_u   : rp_i;
    const int2* pr = isU ? pair_u : pair_i;
    const float* emb = isU ? embI : embU;
    int s0 = rp[r], s1 = rp[r + 1];
    float ax0 = 0.f, ay0 = 0.f, az0 = 0.f, aw0 = 0.f;
    float ax1 = 0.f, ay1 = 0.f, az1 = 0.f, aw1 = 0.f;
    for (int base = s0; base < s1; base += 64) {
      int lim = s1 - base; if (lim > 64) lim = 64;
      int sj = 0; float wj = 0.f;
      if (lane < lim) {
        int2 pw = pr[base + lane];
        sj = pw.x; wj = __int_as_float(pw.y);
      }
      for (int j = 0; j < lim; j += 8) {
        int m0 = j + grp;        // <= 59
        int m1 = j + 4 + grp;    // <= 63
        int   a0 = __shfl(sj, m0); float q0 = __shfl(wj, m0);
        int   a1 = __shfl(sj, m1); float q1 = __shfl(wj, m1);
        float4 e0 = reinterpret_cast<const float4*>(emb + ((size_t)a0 << 6))[sub];
        float4 e1 = reinterpret_cast<const float4*>(emb + ((size_t)a1 << 6))[sub];
        ax0 += q0 * e0.x; ay0 += q0 * e0.y; az0 += q0 * e0.z; aw0 += q0 * e0.w;
        ax1 += q1 * e1.x; ay1 += q1 * e1.y; az1 += q1 * e1.z; aw1 += q1 * e1.w;
      }
    }
    float ax = ax0 + ax1, ay = ay0 + ay1, az = az0 + az1, aw = aw0 + aw1;
    ax += __shfl_xor(ax, 16); ay += __shfl_xor(ay, 16);
    az += __shfl_xor(az, 16); aw += __shfl_xor(aw, 16);
    ax += __shfl_xor(ax, 32); ay += __shfl_xor(ay, 32);
    az += __shfl_xor(az, 32); aw += __shfl_xor(aw, 32);
    if (lane < 16) {
      float4 o; o.x = ax; o.y = ay; o.z = az; o.w = aw;
      if (!isU) {
        reinterpret_cast<float4*>(aggi + ((size_t)r << 6))[sub] = o;
      } else {
        reinterpret_cast<float4*>(unext + ((size_t)r << 6))[sub] = o;
        float4 si;
        if (usum_init) si = reinterpret_cast<const float4*>(usum_init + ((size_t)r << 6))[sub];
        else           si = reinterpret_cast<float4*>(usum + ((size_t)r << 6))[sub];
        float4 s; s.x = si.x + ax; s.y = si.y + ay; s.z = si.z + az; s.w = si.w + aw;
        reinterpret_cast<float4*>(usum + ((size_t)r << 6))[sub] = s;
      }
    }
  }
}

// ---------------- gate + item update (one wave per item) ----------------
__global__ __launch_bounds__(256) void gate_kernel(const float* __restrict__ Wa,
                                                   const float* __restrict__ Wab,
                                                   const float* __restrict__ Wb,
                                                   const float* __restrict__ Wbb,
                                                   const float* __restrict__ kg_item,
                                                   const float* __restrict__ agg_i,
                                                   const float* __restrict__ i_sum_init,
                                                   float* __restrict__ i_next,
                                                   float* __restrict__ i_sum) {
  __shared__ float at[DD * 65];   // transposed, padded (conflict-free)
  __shared__ float bt[DD * 65];
  for (int m = threadIdx.x; m < DD * DD; m += blockDim.x) {
    int o = m >> 6, d = m & 63;
    at[d * 65 + o] = Wa[m];
    bt[d * 65 + o] = Wb[m];
  }
  __syncthreads();
  int lane = threadIdx.x & 63, wid = threadIdx.x >> 6;
  int wpg = gridDim.x * (blockDim.x >> 6);
  float wab = Wab[lane], wbb = Wbb[lane];
  for (int i = blockIdx.x * (blockDim.x >> 6) + wid; i < NIs; i += wpg) {
    float kg = kg_item[i * DD + lane];
    float ag = agg_i[i * DD + lane];
    float acca = 0.f, accb = 0.f;
#pragma unroll
    for (int d = 0; d < DD; ++d) {
      float kd = __shfl(kg, d);
      float ad = __shfl(ag, d);
      acca += kd * at[d * 65 + lane];
      accb += ad * bt[d * 65 + lane];
    }
    float g = 1.f / (1.f + __expf(-(acca + wab + accb + wbb)));
    float inew = g * kg + (1.f - g) * ag;
    i_next[i * DD + lane] = inew;
    if (i_sum_init) i_sum[i * DD + lane] = i_sum_init[i * DD + lane] + inew;
    else            i_sum[i * DD + lane] += inew;
  }
}

// ---------------- BPR loss ----------------
__global__ __launch_bounds__(256) void loss_kernel(const float* __restrict__ u_sum,
                                                   const float* __restrict__ i_sum,
                                                   const int* __restrict__ user,
                                                   const int* __restrict__ pos,
                                                   const int* __restrict__ neg,
                                                   float* acc) {
  int lane = threadIdx.x & 63, wid = threadIdx.x >> 6;
  int wpg = gridDim.x * (blockDim.x >> 6);
  float lacc = 0.f, l2acc = 0.f;
  for (int b = blockIdx.x * (blockDim.x >> 6) + wid; b < BB; b += wpg) {
    float u = u_sum[user[b] * DD + lane];
    float p = i_sum[pos[b] * DD + lane];
    float n = i_sum[neg[b] * DD + lane];
    float ps = wave_sum_f(u * p);
    float ns = wave_sum_f(u * n);
    float sq = wave_sum_f(u * u + p * p + n * n);
    if (lane == 0) {
      float x = ps - ns;
      float sig = 1.f / (1.f + expf(-x));
      lacc += logf(sig + 1e-10f);
      l2acc += sq;
    }
  }
  if (lane == 0) {
    atomicAdd(&acc[0], lacc);
    atomicAdd(&acc[1], l2acc);
  }
}

__global__ void final_kernel(const float* acc, float* out) {
  out[0] = -acc[0] / (float)BB + REGf * (acc[1] / (float)BB);
}

// ---------------- host ----------------

extern "C" void kernel_launch(void* const* d_in, const int* in_sizes, int n_in,
                              void* d_out, int out_size, void* d_ws, size_t ws_size,
                              hipStream_t stream) {
  const float* UE   = (const float*)d_in[0];
  const float* IE   = (const float*)d_in[1];
  const float* EE   = (const float*)d_in[2];
  const float* RE   = (const float*)d_in[3];
  const float* Wkw  = (const float*)d_in[4];
  const float* Wkb  = (const float*)d_in[5];
  const float* Waw  = (const float*)d_in[6];
  const float* Wab  = (const float*)d_in[7];
  const float* Wbw  = (const float*)d_in[8];
  const float* Wbb  = (const float*)d_in[9];
  const float* enorm = (const float*)d_in[10];
  const int* user   = (const int*)d_in[11];
  const int* pos    = (const int*)d_in[12];
  const int* neg    = (const int*)d_in[13];
  const int* edge_u = (const int*)d_in[14];
  const int* edge_i = (const int*)d_in[15];
  const int* kg_rel = (const int*)d_in[16];
  const int* kg_ent = (const int*)d_in[17];

  size_t off = 0;
  char* base = (char*)d_ws;
  auto take = [&](size_t bytes) -> void* {
    void* p = base + off;
    off += (bytes + 255) & ~(size_t)255;
    return p;
  };
  float* Rt      = (float*)take(LAYERS * NRs * DD * sizeof(float));
  float* cvec    = (float*)take(LAYERS * NRs * sizeof(float));
  float* acc     = (float*)take(8 * sizeof(float));
  int*   gbkt    = (int*)take(NBT * sizeof(int));
  int*   bktbase = (int*)take(NBT * sizeof(int));
  int*   bktcur  = (int*)take(NBT * sizeof(int));
  int*   rp_i    = (int*)take((NIs + 1) * sizeof(int));
  int*   rp_u    = (int*)take((NUs + 1) * sizeof(int));
  int2*  tmp_i   = (int2*)take((size_t)NEDGE * sizeof(int2));
  int2*  tmp_u   = (int2*)take((size_t)NEDGE * sizeof(int2));
  int2*  pair_i  = (int2*)take((size_t)NEDGE * sizeof(int2));
  int2*  pair_u  = (int2*)take((size_t)NEDGE * sizeof(int2));
  float* kg      = (float*)take((size_t)NIs * DD * sizeof(float));
  float* aggi    = (float*)take((size_t)NIs * DD * sizeof(float));
  float* iA      = (float*)take((size_t)NIs * DD * sizeof(float));
  float* iB      = (float*)take((size_t)NIs * DD * sizeof(float));
  float* isum    = (float*)take((size_t)NIs * DD * sizeof(float));
  float* uA      = (float*)take((size_t)NUs * DD * sizeof(float));
  float* uB      = (float*)take((size_t)NUs * DD * sizeof(float));
  float* usum    = (float*)take((size_t)NUs * DD * sizeof(float));
  (void)ws_size; (void)in_sizes; (void)n_in; (void)out_size;

  hipMemsetAsync(gbkt, 0, NBT * sizeof(int), stream);
  hipMemsetAsync(acc, 0, 8 * sizeof(float), stream);

  bhist_kernel<<<NCHK, 256, 0, stream>>>(edge_u, edge_i, gbkt);
  bscan_kernel<<<1, 1024, 0, stream>>>(gbkt, bktbase, bktcur, rp_i, rp_u);
  bscatter_kernel<<<NCHK, 256, 0, stream>>>(edge_u, edge_i, enorm, bktcur, tmp_i, tmp_u);
  bsort_kernel<<<NBT, 256, 0, stream>>>(gbkt, bktbase, tmp_i, tmp_u,
                                        pair_i, pair_u, rp_i, rp_u);
  rt_kernel<<<LAYERS * NRs, 64, 0, stream>>>(RE, Wkw, Wkb, Rt, cvec);

  const float* u_cur = UE;
  const float* i_cur = IE;
  float* unext[2] = {uA, uB};
  float* inext[2] = {iA, iB};
  for (int l = 0; l < LAYERS; ++l) {
    attn_kernel<<<2048, 256, 0, stream>>>(EE, Rt + l * NRs * DD, cvec + l * NRs,
                                          kg_ent, kg_rel, i_cur, kg);
    // fused: agg_i (items) + agg_u/u_next/u_sum (users) in one dispatch
    agg2_kernel<<<2048, 256, 0, stream>>>(rp_i, pair_i, u_cur, aggi,
                                          rp_u, pair_u, i_cur, unext[l],
                                          usum, (l == 0) ? UE : nullptr);
    // gate + item update + fused i_sum update
    gate_kernel<<<2048, 256, 0, stream>>>(Waw + (size_t)l * DD * DD, Wab + l * DD,
                                          Wbw + (size_t)l * DD * DD, Wbb + l * DD,
                                          kg, aggi, (l == 0) ? IE : nullptr,
                                          inext[l], isum);
    u_cur = unext[l];
    i_cur = inext[l];
  }

  loss_kernel<<<1024, 256, 0, stream>>>(usum, isum, user, pos, neg, acc);
  final_kernel<<<1, 1, 0, stream>>>(acc, (float*)d_out);
}

// Round 6
// 941.086 us; speedup vs baseline: 1.4390x; 1.0912x over previous
//
#include <hip/hip_runtime.h>
#include <math.h>

constexpr int DD    = 64;        // embedding dim
constexpr int KK    = 16;        // kg neighbors per item
constexpr int NUs   = 100000;    // users
constexpr int NIs   = 50000;     // items
constexpr int NEs   = 200000;    // entities
constexpr int NRs   = 64;        // relations
constexpr int NEDGE = 2000000;   // edges
constexpr int LAYERS = 2;
constexpr int BB    = 4096;      // batch
constexpr float REGf = 1e-4f;

// bucket CSR build
constexpr int SUBB  = 256;                         // destinations per bucket
constexpr int NB_I  = (NIs + SUBB - 1) / SUBB;     // 196
constexpr int NB_U  = (NUs + SUBB - 1) / SUBB;     // 391
constexpr int NBT   = NB_I + NB_U;                 // 587
constexpr int CH    = 8192;                        // edges per block chunk
constexpr int NCHK  = (NEDGE + CH - 1) / CH;       // 245

__device__ __forceinline__ float wave_sum_f(float x) {
#pragma unroll
  for (int off = 32; off > 0; off >>= 1) x += __shfl_xor(x, off);
  return x;
}

// ---------------- CSR build: two-level bucket counting sort ----------------

// A) global bucket histogram via per-block LDS hist (one global atomic per
//    (block,bucket) instead of per edge).
__global__ __launch_bounds__(256) void bhist_kernel(const int* __restrict__ edge_u,
                                                    const int* __restrict__ edge_i,
                                                    int* __restrict__ gbkt) {
  __shared__ int lcnt[NBT];
  for (int b = threadIdx.x; b < NBT; b += 256) lcnt[b] = 0;
  __syncthreads();
  int base = blockIdx.x * CH;
  for (int k = threadIdx.x; k < CH; k += 256) {
    int e = base + k;
    if (e < NEDGE) {
      atomicAdd(&lcnt[edge_i[e] >> 8], 1);
      atomicAdd(&lcnt[NB_I + (edge_u[e] >> 8)], 1);
    }
  }
  __syncthreads();
  for (int b = threadIdx.x; b < NBT; b += 256) {
    int c = lcnt[b];
    if (c) atomicAdd(&gbkt[b], c);
  }
}

// B) segmented exclusive scan of the 587 bucket totals (items | users);
//    writes bucket bases and initializes scatter cursors; writes rp[n].
__global__ __launch_bounds__(1024) void bscan_kernel(const int* __restrict__ gbkt,
                                                     int* __restrict__ bktbase,
                                                     int* __restrict__ bktcur,
                                                     int* rp_i, int* rp_u) {
  __shared__ int sv[1024];
  int tid = threadIdx.x;
  int x = (tid < NBT) ? gbkt[tid] : 0;
  bool segU = (tid >= NB_I);
  int v = x;
  sv[tid] = v;
  __syncthreads();
  for (int off = 1; off < 1024; off <<= 1) {
    int y = 0;
    if (tid >= off) {
      int o = tid - off;
      if ((o >= NB_I) == segU) y = sv[o];
    }
    __syncthreads();
    v += y;
    sv[tid] = v;
    __syncthreads();
  }
  if (tid < NBT) {
    int ex = v - x;
    bktbase[tid] = ex;
    bktcur[tid] = ex;
  }
  if (tid == 0) { rp_i[NIs] = NEDGE; rp_u[NUs] = NEDGE; }
}

// C) scatter edges bucket-grouped. Per-block LDS hist -> one global atomic per
//    (block,bucket) reserves a contiguous run -> writes are clustered runs
//    inside each bucket region (L2-line coalesced).
//    Key packs (dest & 255) << 20 | src  (src < 2^17 fits in 20 bits).
__global__ __launch_bounds__(256) void bscatter_kernel(const int* __restrict__ edge_u,
                                                       const int* __restrict__ edge_i,
                                                       const float* __restrict__ enorm,
                                                       int* __restrict__ bktcur,
                                                       int2* __restrict__ tmp_i,
                                                       int2* __restrict__ tmp_u) {
  __shared__ int lcnt[NBT];
  __shared__ int lbase[NBT];
  for (int b = threadIdx.x; b < NBT; b += 256) lcnt[b] = 0;
  __syncthreads();
  int base = blockIdx.x * CH;
  for (int k = threadIdx.x; k < CH; k += 256) {
    int e = base + k;
    if (e < NEDGE) {
      atomicAdd(&lcnt[edge_i[e] >> 8], 1);
      atomicAdd(&lcnt[NB_I + (edge_u[e] >> 8)], 1);
    }
  }
  __syncthreads();
  for (int b = threadIdx.x; b < NBT; b += 256) {
    int c = lcnt[b];
    lbase[b] = c ? atomicAdd(&bktcur[b], c) : 0;
    lcnt[b] = 0;
  }
  __syncthreads();
  for (int k = threadIdx.x; k < CH; k += 256) {
    int e = base + k;
    if (e < NEDGE) {
      int it = edge_i[e], u = edge_u[e];
      int wb = __float_as_int(enorm[e]);
      int bi = it >> 8;
      int p = lbase[bi] + atomicAdd(&lcnt[bi], 1);
      tmp_i[p] = make_int2(((it & 255) << 20) | u, wb);
      int bu = NB_I + (u >> 8);
      int q = lbase[bu] + atomicAdd(&lcnt[bu], 1);
      tmp_u[q] = make_int2(((u & 255) << 20) | it, wb);
    }
  }
}

// D) per-bucket counting sort into final CSR order + rp write. All random
//    work in LDS; global writes confined to this bucket's contiguous region.
__global__ __launch_bounds__(256) void bsort_kernel(const int* __restrict__ gbkt,
                                                    const int* __restrict__ bktbase,
                                                    const int2* __restrict__ tmp_i,
                                                    const int2* __restrict__ tmp_u,
                                                    int2* __restrict__ pair_i,
                                                    int2* __restrict__ pair_u,
                                                    int* __restrict__ rp_i,
                                                    int* __restrict__ rp_u) {
  int b = blockIdx.x;
  bool isI = (b < NB_I);
  const int2* tmp = isI ? tmp_i : tmp_u;
  int2* po = isI ? pair_i : pair_u;
  int* rp = isI ? rp_i : rp_u;
  int ndst = isI ? NIs : NUs;
  int localb = isI ? b : b - NB_I;
  int start = bktbase[b];
  int size = gbkt[b];
  __shared__ int dcnt[256];
  __shared__ int dpos[256];
  __shared__ int wt[4];
  int tid = threadIdx.x;
  dcnt[tid] = 0;
  __syncthreads();
  for (int k = tid; k < size; k += 256) atomicAdd(&dcnt[tmp[start + k].x >> 20], 1);
  __syncthreads();
  int c = dcnt[tid];
  int lane = tid & 63, wid = tid >> 6;
  int v = c;
#pragma unroll
  for (int off = 1; off < 64; off <<= 1) {
    int y = __shfl_up(v, off);
    if (lane >= off) v += y;
  }
  if (lane == 63) wt[wid] = v;
  __syncthreads();
  int woff = 0;
#pragma unroll
  for (int w = 0; w < 4; ++w)
    if (w < wid) woff += wt[w];
  int excl = woff + v - c;
  dpos[tid] = excl;
  int idx = localb * 256 + tid;
  if (idx < ndst) rp[idx] = start + excl;
  dcnt[tid] = 0;
  __syncthreads();
  for (int k = tid; k < size; k += 256) {
    int2 pw = tmp[start + k];
    int sub = pw.x >> 20;
    int j = dpos[sub] + atomicAdd(&dcnt[sub], 1);
    po[start + j] = make_int2(pw.x & 0xFFFFF, pw.y);
  }
}

// ---------------- relation-space precompute ----------------
// Rt[l][n][d] = sum_o RE[n][o] * (Wk[l][o][d] + Wk[l][o][D+d])
// cvec[l][n]  = sum_o RE[n][o] * Wkb[l][o]
__global__ __launch_bounds__(64) void rt_kernel(const float* __restrict__ RE,
                                                const float* __restrict__ Wkw,
                                                const float* __restrict__ Wkb,
                                                float* Rt, float* cvec) {
  int l = blockIdx.x >> 6;
  int n = blockIdx.x & 63;
  int d = threadIdx.x;
  const float* W  = Wkw + (size_t)l * DD * 2 * DD;
  const float* re = RE + n * DD;
  float acc = 0.f;
  for (int o = 0; o < DD; ++o) {
    float w = W[o * 2 * DD + d] + W[o * 2 * DD + DD + d];
    acc += re[o] * w;
  }
  Rt[(l * NRs + n) * DD + d] = acc;
  float p = re[d] * Wkb[l * DD + d];
  p = wave_sum_f(p);
  if (d == 0) cvec[l * NRs + n] = p;
}

// ---------------- KG attention: one 16-lane group per item ----------------
// 4 independent item-streams per wave; all 16 entity-row gathers issued
// back-to-back into registers (compile-time unroll -> 16 outstanding loads).
// Rt_l (16KB) and c_l (256B) are read directly from global: every block
// touches them -> L1-hot after first touch (no LDS staging needed).
__global__ __launch_bounds__(256) void attn_kernel(const float* __restrict__ EE,
                                                   const float* __restrict__ Rt_l,
                                                   const float* __restrict__ c_l,
                                                   const int* __restrict__ kg_ent,
                                                   const int* __restrict__ kg_rel,
                                                   const float* __restrict__ i_cur,
                                                   float* __restrict__ kg_item) {
  int tid = threadIdx.x;
  int l16 = tid & 15;                       // float4 slot within the row
  int gbase = ((tid & 63) >> 4) << 4;       // group's base lane within wave
  int gid = blockIdx.x * 16 + (tid >> 4);   // global group id
  int ngrp = gridDim.x * 16;
  for (int i = gid; i < NIs; i += ngrp) {
    float4 ic = reinterpret_cast<const float4*>(i_cur + ((size_t)i << 6))[l16];
    int ent = kg_ent[i * KK + l16];         // lane l16 holds neighbor l16
    int rel = kg_rel[i * KK + l16];
    float4 vk[KK];
#pragma unroll
    for (int k = 0; k < KK; ++k) {
      int e = __shfl(ent, gbase + k);
      vk[k] = reinterpret_cast<const float4*>(EE + ((size_t)e << 6))[l16];
    }
    float sc[KK];
#pragma unroll
    for (int k = 0; k < KK; ++k) {
      int rl = __shfl(rel, gbase + k);
      float4 rt = reinterpret_cast<const float4*>(Rt_l + ((size_t)rl << 6))[l16];
      float p = vk[k].x * ic.x * rt.x + vk[k].y * ic.y * rt.y
              + vk[k].z * ic.z * rt.z + vk[k].w * ic.w * rt.w;
      p += __shfl_xor(p, 1); p += __shfl_xor(p, 2);
      p += __shfl_xor(p, 4); p += __shfl_xor(p, 8);   // group-wide score
      float s = p + c_l[rl];
      sc[k] = (s >= 0.f) ? s : 0.2f * s;    // leaky_relu 0.2
    }
    float m = sc[0];
#pragma unroll
    for (int k = 1; k < KK; ++k) m = fmaxf(m, sc[k]);
    float ssum = 0.f;
#pragma unroll
    for (int k = 0; k < KK; ++k) { sc[k] = __expf(sc[k] - m); ssum += sc[k]; }
    float inv = 1.f / ssum;
    float4 o = make_float4(0.f, 0.f, 0.f, 0.f);
#pragma unroll
    for (int k = 0; k < KK; ++k) {
      float a = sc[k] * inv;
      o.x += a * vk[k].x; o.y += a * vk[k].y;
      o.z += a * vk[k].z; o.w += a * vk[k].w;
    }
    reinterpret_cast<float4*>(kg_item + ((size_t)i << 6))[l16] = o;
  }
}

// ---------------- fused dual-direction CSR segment-sum ----------------
// One 16-lane group per destination row (4 row-streams per wave).
// 16 lanes x float4 = the 256B row; per 16-edge batch, two interleaved
// accumulator chains with compile-time unroll -> 16 outstanding gathers.
// No cross-lane reduction needed: the group IS the row. Tail handled by
// wj=0 lanes (gather row 0 with weight 0 -> L1-hot, harmless).
__global__ __launch_bounds__(256) void agg2_kernel(
    const int* __restrict__ rp_i, const int2* __restrict__ pair_i,
    const float* __restrict__ embU, float* __restrict__ aggi,
    const int* __restrict__ rp_u, const int2* __restrict__ pair_u,
    const float* __restrict__ embI, float* __restrict__ unext,
    float* __restrict__ usum, const float* __restrict__ usum_init) {
  int tid = threadIdx.x;
  int l16 = tid & 15;
  int gbase = ((tid & 63) >> 4) << 4;
  int gid = blockIdx.x * 16 + (tid >> 4);
  int ngrp = gridDim.x * 16;
  const int total = NIs + NUs;
  for (int row = gid; row < total; row += ngrp) {
    bool isU = row >= NIs;
    int r = isU ? (row - NIs) : row;
    const int*  rp = isU ? rp_u   : rp_i;
    const int2* pr = isU ? pair_u : pair_i;
    const float* emb = isU ? embI : embU;
    int s0 = rp[r], s1 = rp[r + 1];
    float4 accA = make_float4(0.f, 0.f, 0.f, 0.f);
    float4 accB = make_float4(0.f, 0.f, 0.f, 0.f);
    for (int base = s0; base < s1; base += 16) {
      int lim = s1 - base;
      int sj = 0; float wj = 0.f;
      if (l16 < lim) {
        int2 pw = pr[base + l16];
        sj = pw.x; wj = __int_as_float(pw.y);
      }
#pragma unroll
      for (int jj = 0; jj < 8; ++jj) {
        int aA = __shfl(sj, gbase + jj);     float qA = __shfl(wj, gbase + jj);
        int aB = __shfl(sj, gbase + 8 + jj); float qB = __shfl(wj, gbase + 8 + jj);
        float4 eA = reinterpret_cast<const float4*>(emb + ((size_t)aA << 6))[l16];
        float4 eB = reinterpret_cast<const float4*>(emb + ((size_t)aB << 6))[l16];
        accA.x += qA * eA.x; accA.y += qA * eA.y; accA.z += qA * eA.z; accA.w += qA * eA.w;
        accB.x += qB * eB.x; accB.y += qB * eB.y; accB.z += qB * eB.z; accB.w += qB * eB.w;
      }
    }
    float4 o;
    o.x = accA.x + accB.x; o.y = accA.y + accB.y;
    o.z = accA.z + accB.z; o.w = accA.w + accB.w;
    if (!isU) {
      reinterpret_cast<float4*>(aggi + ((size_t)r << 6))[l16] = o;
    } else {
      reinterpret_cast<float4*>(unext + ((size_t)r << 6))[l16] = o;
      float4 si;
      if (usum_init) si = reinterpret_cast<const float4*>(usum_init + ((size_t)r << 6))[l16];
      else           si = reinterpret_cast<float4*>(usum + ((size_t)r << 6))[l16];
      float4 s;
      s.x = si.x + o.x; s.y = si.y + o.y; s.z = si.z + o.z; s.w = si.w + o.w;
      reinterpret_cast<float4*>(usum + ((size_t)r << 6))[l16] = s;
    }
  }
}

// ---------------- gate + item update (one wave per item) ----------------
__global__ __launch_bounds__(256) void gate_kernel(const float* __restrict__ Wa,
                                                   const float* __restrict__ Wab,
                                                   const float* __restrict__ Wb,
                                                   const float* __restrict__ Wbb,
                                                   const float* __restrict__ kg_item,
                                                   const float* __restrict__ agg_i,
                                                   const float* __restrict__ i_sum_init,
                                                   float* __restrict__ i_next,
                                                   float* __restrict__ i_sum) {
  __shared__ float at[DD * 65];   // transposed, padded (conflict-free)
  __shared__ float bt[DD * 65];
  for (int m = threadIdx.x; m < DD * DD; m += blockDim.x) {
    int o = m >> 6, d = m & 63;
    at[d * 65 + o] = Wa[m];
    bt[d * 65 + o] = Wb[m];
  }
  __syncthreads();
  int lane = threadIdx.x & 63, wid = threadIdx.x >> 6;
  int wpg = gridDim.x * (blockDim.x >> 6);
  float wab = Wab[lane], wbb = Wbb[lane];
  for (int i = blockIdx.x * (blockDim.x >> 6) + wid; i < NIs; i += wpg) {
    float kg = kg_item[i * DD + lane];
    float ag = agg_i[i * DD + lane];
    float acca = 0.f, accb = 0.f;
#pragma unroll
    for (int d = 0; d < DD; ++d) {
      float kd = __shfl(kg, d);
      float ad = __shfl(ag, d);
      acca += kd * at[d * 65 + lane];
      accb += ad * bt[d * 65 + lane];
    }
    float g = 1.f / (1.f + __expf(-(acca + wab + accb + wbb)));
    float inew = g * kg + (1.f - g) * ag;
    i_next[i * DD + lane] = inew;
    if (i_sum_init) i_sum[i * DD + lane] = i_sum_init[i * DD + lane] + inew;
    else            i_sum[i * DD + lane] += inew;
  }
}

// ---------------- BPR loss ----------------
__global__ __launch_bounds__(256) void loss_kernel(const float* __restrict__ u_sum,
                                                   const float* __restrict__ i_sum,
                                                   const int* __restrict__ user,
                                                   const int* __restrict__ pos,
                                                   const int* __restrict__ neg,
                                                   float* acc) {
  int lane = threadIdx.x & 63, wid = threadIdx.x >> 6;
  int wpg = gridDim.x * (blockDim.x >> 6);
  float lacc = 0.f, l2acc = 0.f;
  for (int b = blockIdx.x * (blockDim.x >> 6) + wid; b < BB; b += wpg) {
    float u = u_sum[user[b] * DD + lane];
    float p = i_sum[pos[b] * DD + lane];
    float n = i_sum[neg[b] * DD + lane];
    float ps = wave_sum_f(u * p);
    float ns = wave_sum_f(u * n);
    float sq = wave_sum_f(u * u + p * p + n * n);
    if (lane == 0) {
      float x = ps - ns;
      float sig = 1.f / (1.f + expf(-x));
      lacc += logf(sig + 1e-10f);
      l2acc += sq;
    }
  }
  if (lane == 0) {
    atomicAdd(&acc[0], lacc);
    atomicAdd(&acc[1], l2acc);
  }
}

__global__ void final_kernel(const float* acc, float* out) {
  out[0] = -acc[0] / (float)BB + REGf * (acc[1] / (float)BB);
}

// ---------------- host ----------------

extern "C" void kernel_launch(void* const* d_in, const int* in_sizes, int n_in,
                              void* d_out, int out_size, void* d_ws, size_t ws_size,
                              hipStream_t stream) {
  const float* UE   = (const float*)d_in[0];
  const float* IE   = (const float*)d_in[1];
  const float* EE   = (const float*)d_in[2];
  const float* RE   = (const float*)d_in[3];
  const float* Wkw  = (const float*)d_in[4];
  const float* Wkb  = (const float*)d_in[5];
  const float* Waw  = (const float*)d_in[6];
  const float* Wab  = (const float*)d_in[7];
  const float* Wbw  = (const float*)d_in[8];
  const float* Wbb  = (const float*)d_in[9];
  const float* enorm = (const float*)d_in[10];
  const int* user   = (const int*)d_in[11];
  const int* pos    = (const int*)d_in[12];
  const int* neg    = (const int*)d_in[13];
  const int* edge_u = (const int*)d_in[14];
  const int* edge_i = (const int*)d_in[15];
  const int* kg_rel = (const int*)d_in[16];
  const int* kg_ent = (const int*)d_in[17];

  size_t off = 0;
  char* base = (char*)d_ws;
  auto take = [&](size_t bytes) -> void* {
    void* p = base + off;
    off += (bytes + 255) & ~(size_t)255;
    return p;
  };
  float* Rt      = (float*)take(LAYERS * NRs * DD * sizeof(float));
  float* cvec    = (float*)take(LAYERS * NRs * sizeof(float));
  float* acc     = (float*)take(8 * sizeof(float));
  int*   gbkt    = (int*)take(NBT * sizeof(int));
  int*   bktbase = (int*)take(NBT * sizeof(int));
  int*   bktcur  = (int*)take(NBT * sizeof(int));
  int*   rp_i    = (int*)take((NIs + 1) * sizeof(int));
  int*   rp_u    = (int*)take((NUs + 1) * sizeof(int));
  int2*  tmp_i   = (int2*)take((size_t)NEDGE * sizeof(int2));
  int2*  tmp_u   = (int2*)take((size_t)NEDGE * sizeof(int2));
  int2*  pair_i  = (int2*)take((size_t)NEDGE * sizeof(int2));
  int2*  pair_u  = (int2*)take((size_t)NEDGE * sizeof(int2));
  float* kg      = (float*)take((size_t)NIs * DD * sizeof(float));
  float* aggi    = (float*)take((size_t)NIs * DD * sizeof(float));
  float* iA      = (float*)take((size_t)NIs * DD * sizeof(float));
  float* iB      = (float*)take((size_t)NIs * DD * sizeof(float));
  float* isum    = (float*)take((size_t)NIs * DD * sizeof(float));
  float* uA      = (float*)take((size_t)NUs * DD * sizeof(float));
  float* uB      = (float*)take((size_t)NUs * DD * sizeof(float));
  float* usum    = (float*)take((size_t)NUs * DD * sizeof(float));
  (void)ws_size; (void)in_sizes; (void)n_in; (void)out_size;

  hipMemsetAsync(gbkt, 0, NBT * sizeof(int), stream);
  hipMemsetAsync(acc, 0, 8 * sizeof(float), stream);

  bhist_kernel<<<NCHK, 256, 0, stream>>>(edge_u, edge_i, gbkt);
  bscan_kernel<<<1, 1024, 0, stream>>>(gbkt, bktbase, bktcur, rp_i, rp_u);
  bscatter_kernel<<<NCHK, 256, 0, stream>>>(edge_u, edge_i, enorm, bktcur, tmp_i, tmp_u);
  bsort_kernel<<<NBT, 256, 0, stream>>>(gbkt, bktbase, tmp_i, tmp_u,
                                        pair_i, pair_u, rp_i, rp_u);
  rt_kernel<<<LAYERS * NRs, 64, 0, stream>>>(RE, Wkw, Wkb, Rt, cvec);

  const float* u_cur = UE;
  const float* i_cur = IE;
  float* unext[2] = {uA, uB};
  float* inext[2] = {iA, iB};
  for (int l = 0; l < LAYERS; ++l) {
    attn_kernel<<<2048, 256, 0, stream>>>(EE, Rt + l * NRs * DD, cvec + l * NRs,
                                          kg_ent, kg_rel, i_cur, kg);
    // fused: agg_i (items) + agg_u/u_next/u_sum (users) in one dispatch
    agg2_kernel<<<2048, 256, 0, stream>>>(rp_i, pair_i, u_cur, aggi,
                                          rp_u, pair_u, i_cur, unext[l],
                                          usum, (l == 0) ? UE : nullptr);
    // gate + item update + fused i_sum update
    gate_kernel<<<2048, 256, 0, stream>>>(Waw + (size_t)l * DD * DD, Wab + l * DD,
                                          Wbw + (size_t)l * DD * DD, Wbb + l * DD,
                                          kg, aggi, (l == 0) ? IE : nullptr,
                                          inext[l], isum);
    u_cur = unext[l];
    i_cur = inext[l];
  }

  loss_kernel<<<1024, 256, 0, stream>>>(usum, isum, user, pos, neg, acc);
  final_kernel<<<1, 1, 0, stream>>>(acc, (float*)d_out);
}

// Round 8
// 835.791 us; speedup vs baseline: 1.6203x; 1.1260x over previous
//
#include <hip/hip_runtime.h>
#include <math.h>

constexpr int DD    = 64;        // embedding dim
constexpr int KK    = 16;        // kg neighbors per item
constexpr int NUs   = 100000;    // users
constexpr int NIs   = 50000;     // items
constexpr int NEs   = 200000;    // entities
constexpr int NRs   = 64;        // relations
constexpr int NEDGE = 2000000;   // edges
constexpr int LAYERS = 2;
constexpr int BB    = 4096;      // batch
constexpr float REGf = 1e-4f;

// bucket CSR build
constexpr int SUBB  = 256;                         // destinations per bucket
constexpr int NB_I  = (NIs + SUBB - 1) / SUBB;     // 196
constexpr int NB_U  = (NUs + SUBB - 1) / SUBB;     // 391
constexpr int NBT   = NB_I + NB_U;                 // 587
constexpr int CH    = 8192;                        // edges per block chunk
constexpr int NCHK  = (NEDGE + CH - 1) / CH;       // 245

__device__ __forceinline__ float wave_sum_f(float x) {
#pragma unroll
  for (int off = 32; off > 0; off >>= 1) x += __shfl_xor(x, off);
  return x;
}

// ---------------- prep: zero gbkt/acc/done (replaces 2 memsets) ----------------
__global__ __launch_bounds__(256) void prep_kernel(int* gbkt, float* acc, int* done) {
  for (int b = threadIdx.x; b < NBT; b += 256) gbkt[b] = 0;
  if (threadIdx.x < 8) acc[threadIdx.x] = 0.f;
  if (threadIdx.x == 8) *done = 0;
}

// ---------------- CSR build: two-level bucket counting sort ----------------

// A) global bucket histogram via per-block LDS hist.
__global__ __launch_bounds__(256) void bhist_kernel(const int* __restrict__ edge_u,
                                                    const int* __restrict__ edge_i,
                                                    int* __restrict__ gbkt) {
  __shared__ int lcnt[NBT];
  for (int b = threadIdx.x; b < NBT; b += 256) lcnt[b] = 0;
  __syncthreads();
  int base = blockIdx.x * CH;
  for (int k = threadIdx.x; k < CH; k += 256) {
    int e = base + k;
    if (e < NEDGE) {
      atomicAdd(&lcnt[edge_i[e] >> 8], 1);
      atomicAdd(&lcnt[NB_I + (edge_u[e] >> 8)], 1);
    }
  }
  __syncthreads();
  for (int b = threadIdx.x; b < NBT; b += 256) {
    int c = lcnt[b];
    if (c) atomicAdd(&gbkt[b], c);
  }
}

// B) block 0: segmented scan of bucket totals -> bases/cursors + rp[n].
//    blocks 1..8: rt precompute (16 (l,n) pairs per block, one wave each):
//    Rt[l][n][d] = sum_o RE[n][o]*(Wk[l][o][d]+Wk[l][o][D+d]);
//    cvec[l][n]  = sum_o RE[n][o]*Wkb[l][o]
__global__ __launch_bounds__(1024) void bscan_rt_kernel(const int* __restrict__ gbkt,
                                                        int* __restrict__ bktbase,
                                                        int* __restrict__ bktcur,
                                                        int* rp_i, int* rp_u,
                                                        const float* __restrict__ RE,
                                                        const float* __restrict__ Wkw,
                                                        const float* __restrict__ Wkb,
                                                        float* Rt, float* cvec) {
  if (blockIdx.x == 0) {
    __shared__ int sv[1024];
    int tid = threadIdx.x;
    int x = (tid < NBT) ? gbkt[tid] : 0;
    bool segU = (tid >= NB_I);
    int v = x;
    sv[tid] = v;
    __syncthreads();
    for (int off = 1; off < 1024; off <<= 1) {
      int y = 0;
      if (tid >= off) {
        int o = tid - off;
        if ((o >= NB_I) == segU) y = sv[o];
      }
      __syncthreads();
      v += y;
      sv[tid] = v;
      __syncthreads();
    }
    if (tid < NBT) {
      int ex = v - x;
      bktbase[tid] = ex;
      bktcur[tid] = ex;
    }
    if (tid == 0) { rp_i[NIs] = NEDGE; rp_u[NUs] = NEDGE; }
  } else {
    int p = (blockIdx.x - 1) * 16 + (threadIdx.x >> 6);   // 0..127
    int l = p >> 6, n = p & 63;
    int d = threadIdx.x & 63;
    const float* W  = Wkw + (size_t)l * DD * 2 * DD;
    const float* re = RE + n * DD;
    float acc = 0.f;
    for (int o = 0; o < DD; ++o) {
      float w = W[o * 2 * DD + d] + W[o * 2 * DD + DD + d];
      acc += re[o] * w;
    }
    Rt[(l * NRs + n) * DD + d] = acc;
    float pr = re[d] * Wkb[l * DD + d];
    pr = wave_sum_f(pr);
    if (d == 0) cvec[l * NRs + n] = pr;
  }
}

// C) scatter edges bucket-grouped (clustered runs per (block,bucket)).
//    Key packs (dest & 255) << 20 | src.
__global__ __launch_bounds__(256) void bscatter_kernel(const int* __restrict__ edge_u,
                                                       const int* __restrict__ edge_i,
                                                       const float* __restrict__ enorm,
                                                       int* __restrict__ bktcur,
                                                       int2* __restrict__ tmp_i,
                                                       int2* __restrict__ tmp_u) {
  __shared__ int lcnt[NBT];
  __shared__ int lbase[NBT];
  for (int b = threadIdx.x; b < NBT; b += 256) lcnt[b] = 0;
  __syncthreads();
  int base = blockIdx.x * CH;
  for (int k = threadIdx.x; k < CH; k += 256) {
    int e = base + k;
    if (e < NEDGE) {
      atomicAdd(&lcnt[edge_i[e] >> 8], 1);
      atomicAdd(&lcnt[NB_I + (edge_u[e] >> 8)], 1);
    }
  }
  __syncthreads();
  for (int b = threadIdx.x; b < NBT; b += 256) {
    int c = lcnt[b];
    lbase[b] = c ? atomicAdd(&bktcur[b], c) : 0;
    lcnt[b] = 0;
  }
  __syncthreads();
  for (int k = threadIdx.x; k < CH; k += 256) {
    int e = base + k;
    if (e < NEDGE) {
      int it = edge_i[e], u = edge_u[e];
      int wb = __float_as_int(enorm[e]);
      int bi = it >> 8;
      int p = lbase[bi] + atomicAdd(&lcnt[bi], 1);
      tmp_i[p] = make_int2(((it & 255) << 20) | u, wb);
      int bu = NB_I + (u >> 8);
      int q = lbase[bu] + atomicAdd(&lcnt[bu], 1);
      tmp_u[q] = make_int2(((u & 255) << 20) | it, wb);
    }
  }
}

// D) per-bucket counting sort into final CSR order + rp write.
__global__ __launch_bounds__(256) void bsort_kernel(const int* __restrict__ gbkt,
                                                    const int* __restrict__ bktbase,
                                                    const int2* __restrict__ tmp_i,
                                                    const int2* __restrict__ tmp_u,
                                                    int2* __restrict__ pair_i,
                                                    int2* __restrict__ pair_u,
                                                    int* __restrict__ rp_i,
                                                    int* __restrict__ rp_u) {
  int b = blockIdx.x;
  bool isI = (b < NB_I);
  const int2* tmp = isI ? tmp_i : tmp_u;
  int2* po = isI ? pair_i : pair_u;
  int* rp = isI ? rp_i : rp_u;
  int ndst = isI ? NIs : NUs;
  int localb = isI ? b : b - NB_I;
  int start = bktbase[b];
  int size = gbkt[b];
  __shared__ int dcnt[256];
  __shared__ int dpos[256];
  __shared__ int wt[4];
  int tid = threadIdx.x;
  dcnt[tid] = 0;
  __syncthreads();
  for (int k = tid; k < size; k += 256) atomicAdd(&dcnt[tmp[start + k].x >> 20], 1);
  __syncthreads();
  int c = dcnt[tid];
  int lane = tid & 63, wid = tid >> 6;
  int v = c;
#pragma unroll
  for (int off = 1; off < 64; off <<= 1) {
    int y = __shfl_up(v, off);
    if (lane >= off) v += y;
  }
  if (lane == 63) wt[wid] = v;
  __syncthreads();
  int woff = 0;
#pragma unroll
  for (int w = 0; w < 4; ++w)
    if (w < wid) woff += wt[w];
  int excl = woff + v - c;
  dpos[tid] = excl;
  int idx = localb * 256 + tid;
  if (idx < ndst) rp[idx] = start + excl;
  dcnt[tid] = 0;
  __syncthreads();
  for (int k = tid; k < size; k += 256) {
    int2 pw = tmp[start + k];
    int sub = pw.x >> 20;
    int j = dpos[sub] + atomicAdd(&dcnt[sub], 1);
    po[start + j] = make_int2(pw.x & 0xFFFFF, pw.y);
  }
}

// ---------------- fused layer kernel ----------------
// 16-lane group per row. Item rows [0,NIs): attn (kg in regs) -> agg_i (regs)
// -> gate (LDS-transposed Wa/Wb, group-shfl) -> i_next, i_sum.
// User rows [NIs,NIs+NUs): agg_u -> u_next, u_sum.
// kg_item / agg_i never touch memory.
__global__ __launch_bounds__(256) void layer_kernel(
    const float* __restrict__ EE, const float* __restrict__ Rt_l,
    const float* __restrict__ c_l,
    const int* __restrict__ kg_ent, const int* __restrict__ kg_rel,
    const float* __restrict__ Waw_l, const float* __restrict__ Wab_l,
    const float* __restrict__ Wbw_l, const float* __restrict__ Wbb_l,
    const int* __restrict__ rp_i, const int2* __restrict__ pair_i,
    const int* __restrict__ rp_u, const int2* __restrict__ pair_u,
    const float* __restrict__ u_cur, const float* __restrict__ i_cur,
    float* __restrict__ i_next, float* __restrict__ i_sum,
    const float* __restrict__ i_sum_init,
    float* __restrict__ u_next, float* __restrict__ u_sum,
    const float* __restrict__ u_sum_init) {
  __shared__ float at_s[DD * DD];   // at_s[d*64+o] = Wa[o*64+d] (transposed)
  __shared__ float bt_s[DD * DD];
  for (int m = threadIdx.x; m < DD * DD; m += 256) {
    int o = m >> 6, d = m & 63;
    at_s[d * 64 + o] = Waw_l[m];
    bt_s[d * 64 + o] = Wbw_l[m];
  }
  __syncthreads();
  int tid = threadIdx.x;
  int l16 = tid & 15;
  int gbase = ((tid & 63) >> 4) << 4;
  int gid = blockIdx.x * 16 + (tid >> 4);
  int ngrp = gridDim.x * 16;
  const int total = NIs + NUs;
  for (int row = gid; row < total; row += ngrp) {
    if (row < NIs) {
      int i = row;
      // ---- KG attention ----
      float4 ic = reinterpret_cast<const float4*>(i_cur + ((size_t)i << 6))[l16];
      int ent = kg_ent[i * KK + l16];
      int rel = kg_rel[i * KK + l16];
      float4 vk[KK];
#pragma unroll
      for (int k = 0; k < KK; ++k) {
        int e = __shfl(ent, gbase + k);
        vk[k] = reinterpret_cast<const float4*>(EE + ((size_t)e << 6))[l16];
      }
      float sc[KK];
#pragma unroll
      for (int k = 0; k < KK; ++k) {
        int rl = __shfl(rel, gbase + k);
        float4 rt = reinterpret_cast<const float4*>(Rt_l + ((size_t)rl << 6))[l16];
        float p = vk[k].x * ic.x * rt.x + vk[k].y * ic.y * rt.y
                + vk[k].z * ic.z * rt.z + vk[k].w * ic.w * rt.w;
        p += __shfl_xor(p, 1); p += __shfl_xor(p, 2);
        p += __shfl_xor(p, 4); p += __shfl_xor(p, 8);
        float s = p + c_l[rl];
        sc[k] = (s >= 0.f) ? s : 0.2f * s;   // leaky_relu 0.2
      }
      float mx = sc[0];
#pragma unroll
      for (int k = 1; k < KK; ++k) mx = fmaxf(mx, sc[k]);
      float ssum = 0.f;
#pragma unroll
      for (int k = 0; k < KK; ++k) { sc[k] = __expf(sc[k] - mx); ssum += sc[k]; }
      float inv = 1.f / ssum;
      float4 kg = make_float4(0.f, 0.f, 0.f, 0.f);
#pragma unroll
      for (int k = 0; k < KK; ++k) {
        float a = sc[k] * inv;
        kg.x += a * vk[k].x; kg.y += a * vk[k].y;
        kg.z += a * vk[k].z; kg.w += a * vk[k].w;
      }
      // ---- agg_i (gather user rows) ----
      int s0 = rp_i[i], s1 = rp_i[i + 1];
      float4 accA = make_float4(0.f, 0.f, 0.f, 0.f);
      float4 accB = make_float4(0.f, 0.f, 0.f, 0.f);
      for (int base = s0; base < s1; base += 16) {
        int lim = s1 - base;
        int sj = 0; float wj = 0.f;
        if (l16 < lim) {
          int2 pw = pair_i[base + l16];
          sj = pw.x; wj = __int_as_float(pw.y);
        }
#pragma unroll
        for (int jj = 0; jj < 8; ++jj) {
          int aA = __shfl(sj, gbase + jj);     float qA = __shfl(wj, gbase + jj);
          int aB = __shfl(sj, gbase + 8 + jj); float qB = __shfl(wj, gbase + 8 + jj);
          float4 eA = reinterpret_cast<const float4*>(u_cur + ((size_t)aA << 6))[l16];
          float4 eB = reinterpret_cast<const float4*>(u_cur + ((size_t)aB << 6))[l16];
          accA.x += qA * eA.x; accA.y += qA * eA.y; accA.z += qA * eA.z; accA.w += qA * eA.w;
          accB.x += qB * eB.x; accB.y += qB * eB.y; accB.z += qB * eB.z; accB.w += qB * eB.w;
        }
      }
      float4 ag;
      ag.x = accA.x + accB.x; ag.y = accA.y + accB.y;
      ag.z = accA.z + accB.z; ag.w = accA.w + accB.w;
      // ---- gate: acca = Wa @ kg, accb = Wb @ ag (per-lane 4 outputs) ----
      float4 acca = make_float4(0.f, 0.f, 0.f, 0.f);
      float4 accb = make_float4(0.f, 0.f, 0.f, 0.f);
#pragma unroll
      for (int r = 0; r < 16; ++r) {
        float kx = __shfl(kg.x, gbase + r), ky = __shfl(kg.y, gbase + r);
        float kz = __shfl(kg.z, gbase + r), kw = __shfl(kg.w, gbase + r);
        float axv = __shfl(ag.x, gbase + r), ayv = __shfl(ag.y, gbase + r);
        float azv = __shfl(ag.z, gbase + r), awv = __shfl(ag.w, gbase + r);
        float4 a0 = *reinterpret_cast<const float4*>(&at_s[(4 * r + 0) * 64 + l16 * 4]);
        float4 a1 = *reinterpret_cast<const float4*>(&at_s[(4 * r + 1) * 64 + l16 * 4]);
        float4 a2 = *reinterpret_cast<const float4*>(&at_s[(4 * r + 2) * 64 + l16 * 4]);
        float4 a3 = *reinterpret_cast<const float4*>(&at_s[(4 * r + 3) * 64 + l16 * 4]);
        acca.x += kx * a0.x + ky * a1.x + kz * a2.x + kw * a3.x;
        acca.y += kx * a0.y + ky * a1.y + kz * a2.y + kw * a3.y;
        acca.z += kx * a0.z + ky * a1.z + kz * a2.z + kw * a3.z;
        acca.w += kx * a0.w + ky * a1.w + kz * a2.w + kw * a3.w;
        float4 b0 = *reinterpret_cast<const float4*>(&bt_s[(4 * r + 0) * 64 + l16 * 4]);
        float4 b1 = *reinterpret_cast<const float4*>(&bt_s[(4 * r + 1) * 64 + l16 * 4]);
        float4 b2 = *reinterpret_cast<const float4*>(&bt_s[(4 * r + 2) * 64 + l16 * 4]);
        float4 b3 = *reinterpret_cast<const float4*>(&bt_s[(4 * r + 3) * 64 + l16 * 4]);
        accb.x += axv * b0.x + ayv * b1.x + azv * b2.x + awv * b3.x;
        accb.y += axv * b0.y + ayv * b1.y + azv * b2.y + awv * b3.y;
        accb.z += axv * b0.z + ayv * b1.z + azv * b2.z + awv * b3.z;
        accb.w += axv * b0.w + ayv * b1.w + azv * b2.w + awv * b3.w;
      }
      float4 wab = reinterpret_cast<const float4*>(Wab_l)[l16];
      float4 wbb = reinterpret_cast<const float4*>(Wbb_l)[l16];
      float4 g, inew;
      g.x = 1.f / (1.f + __expf(-(acca.x + wab.x + accb.x + wbb.x)));
      g.y = 1.f / (1.f + __expf(-(acca.y + wab.y + accb.y + wbb.y)));
      g.z = 1.f / (1.f + __expf(-(acca.z + wab.z + accb.z + wbb.z)));
      g.w = 1.f / (1.f + __expf(-(acca.w + wab.w + accb.w + wbb.w)));
      inew.x = g.x * kg.x + (1.f - g.x) * ag.x;
      inew.y = g.y * kg.y + (1.f - g.y) * ag.y;
      inew.z = g.z * kg.z + (1.f - g.z) * ag.z;
      inew.w = g.w * kg.w + (1.f - g.w) * ag.w;
      reinterpret_cast<float4*>(i_next + ((size_t)i << 6))[l16] = inew;
      float4 si;
      if (i_sum_init) si = reinterpret_cast<const float4*>(i_sum_init + ((size_t)i << 6))[l16];
      else            si = reinterpret_cast<float4*>(i_sum + ((size_t)i << 6))[l16];
      float4 so;
      so.x = si.x + inew.x; so.y = si.y + inew.y;
      so.z = si.z + inew.z; so.w = si.w + inew.w;
      reinterpret_cast<float4*>(i_sum + ((size_t)i << 6))[l16] = so;
    } else {
      int r = row - NIs;
      int s0 = rp_u[r], s1 = rp_u[r + 1];
      float4 accA = make_float4(0.f, 0.f, 0.f, 0.f);
      float4 accB = make_float4(0.f, 0.f, 0.f, 0.f);
      for (int base = s0; base < s1; base += 16) {
        int lim = s1 - base;
        int sj = 0; float wj = 0.f;
        if (l16 < lim) {
          int2 pw = pair_u[base + l16];
          sj = pw.x; wj = __int_as_float(pw.y);
        }
#pragma unroll
        for (int jj = 0; jj < 8; ++jj) {
          int aA = __shfl(sj, gbase + jj);     float qA = __shfl(wj, gbase + jj);
          int aB = __shfl(sj, gbase + 8 + jj); float qB = __shfl(wj, gbase + 8 + jj);
          float4 eA = reinterpret_cast<const float4*>(i_cur + ((size_t)aA << 6))[l16];
          float4 eB = reinterpret_cast<const float4*>(i_cur + ((size_t)aB << 6))[l16];
          accA.x += qA * eA.x; accA.y += qA * eA.y; accA.z += qA * eA.z; accA.w += qA * eA.w;
          accB.x += qB * eB.x; accB.y += qB * eB.y; accB.z += qB * eB.z; accB.w += qB * eB.w;
        }
      }
      float4 o;
      o.x = accA.x + accB.x; o.y = accA.y + accB.y;
      o.z = accA.z + accB.z; o.w = accA.w + accB.w;
      reinterpret_cast<float4*>(u_next + ((size_t)r << 6))[l16] = o;
      float4 si;
      if (u_sum_init) si = reinterpret_cast<const float4*>(u_sum_init + ((size_t)r << 6))[l16];
      else            si = reinterpret_cast<float4*>(u_sum + ((size_t)r << 6))[l16];
      float4 s;
      s.x = si.x + o.x; s.y = si.y + o.y; s.z = si.z + o.z; s.w = si.w + o.w;
      reinterpret_cast<float4*>(u_sum + ((size_t)r << 6))[l16] = s;
    }
  }
}

// ---------------- BPR loss (+ last-block final) ----------------
__global__ __launch_bounds__(256) void loss_kernel(const float* __restrict__ u_sum,
                                                   const float* __restrict__ i_sum,
                                                   const int* __restrict__ user,
                                                   const int* __restrict__ pos,
                                                   const int* __restrict__ neg,
                                                   float* acc, int* done, float* out) {
  int lane = threadIdx.x & 63, wid = threadIdx.x >> 6;
  int wpg = gridDim.x * (blockDim.x >> 6);
  float lacc = 0.f, l2acc = 0.f;
  for (int b = blockIdx.x * (blockDim.x >> 6) + wid; b < BB; b += wpg) {
    float u = u_sum[user[b] * DD + lane];
    float p = i_sum[pos[b] * DD + lane];
    float n = i_sum[neg[b] * DD + lane];
    float ps = wave_sum_f(u * p);
    float ns = wave_sum_f(u * n);
    float sq = wave_sum_f(u * u + p * p + n * n);
    if (lane == 0) {
      float x = ps - ns;
      float sig = 1.f / (1.f + expf(-x));
      lacc += logf(sig + 1e-10f);
      l2acc += sq;
    }
  }
  if (lane == 0) {
    atomicAdd(&acc[0], lacc);
    atomicAdd(&acc[1], l2acc);
  }
  __syncthreads();
  if (threadIdx.x == 0) {
    __threadfence();
    int old = atomicAdd(done, 1);
    if (old == gridDim.x - 1) {
      // atomic-read acc at the coherence point (XCD-safe)
      float a0 = atomicAdd(&acc[0], 0.f);
      float a1 = atomicAdd(&acc[1], 0.f);
      out[0] = -a0 / (float)BB + REGf * (a1 / (float)BB);
    }
  }
}

// ---------------- host ----------------

extern "C" void kernel_launch(void* const* d_in, const int* in_sizes, int n_in,
                              void* d_out, int out_size, void* d_ws, size_t ws_size,
                              hipStream_t stream) {
  const float* UE   = (const float*)d_in[0];
  const float* IE   = (const float*)d_in[1];
  const float* EE   = (const float*)d_in[2];
  const float* RE   = (const float*)d_in[3];
  const float* Wkw  = (const float*)d_in[4];
  const float* Wkb  = (const float*)d_in[5];
  const float* Waw  = (const float*)d_in[6];
  const float* Wab  = (const float*)d_in[7];
  const float* Wbw  = (const float*)d_in[8];
  const float* Wbb  = (const float*)d_in[9];
  const float* enorm = (const float*)d_in[10];
  const int* user   = (const int*)d_in[11];
  const int* pos    = (const int*)d_in[12];
  const int* neg    = (const int*)d_in[13];
  const int* edge_u = (const int*)d_in[14];
  const int* edge_i = (const int*)d_in[15];
  const int* kg_rel = (const int*)d_in[16];
  const int* kg_ent = (const int*)d_in[17];

  size_t off = 0;
  char* base = (char*)d_ws;
  auto take = [&](size_t bytes) -> void* {
    void* p = base + off;
    off += (bytes + 255) & ~(size_t)255;
    return p;
  };
  float* Rt      = (float*)take(LAYERS * NRs * DD * sizeof(float));
  float* cvec    = (float*)take(LAYERS * NRs * sizeof(float));
  float* acc     = (float*)take(8 * sizeof(float));
  int*   done    = (int*)take(sizeof(int));
  int*   gbkt    = (int*)take(NBT * sizeof(int));
  int*   bktbase = (int*)take(NBT * sizeof(int));
  int*   bktcur  = (int*)take(NBT * sizeof(int));
  int*   rp_i    = (int*)take((NIs + 1) * sizeof(int));
  int*   rp_u    = (int*)take((NUs + 1) * sizeof(int));
  int2*  tmp_i   = (int2*)take((size_t)NEDGE * sizeof(int2));
  int2*  tmp_u   = (int2*)take((size_t)NEDGE * sizeof(int2));
  int2*  pair_i  = (int2*)take((size_t)NEDGE * sizeof(int2));
  int2*  pair_u  = (int2*)take((size_t)NEDGE * sizeof(int2));
  float* iA      = (float*)take((size_t)NIs * DD * sizeof(float));
  float* iB      = (float*)take((size_t)NIs * DD * sizeof(float));
  float* isum    = (float*)take((size_t)NIs * DD * sizeof(float));
  float* uA      = (float*)take((size_t)NUs * DD * sizeof(float));
  float* uB      = (float*)take((size_t)NUs * DD * sizeof(float));
  float* usum    = (float*)take((size_t)NUs * DD * sizeof(float));
  (void)ws_size; (void)in_sizes; (void)n_in; (void)out_size;

  prep_kernel<<<1, 256, 0, stream>>>(gbkt, acc, done);
  bhist_kernel<<<NCHK, 256, 0, stream>>>(edge_u, edge_i, gbkt);
  bscan_rt_kernel<<<9, 1024, 0, stream>>>(gbkt, bktbase, bktcur, rp_i, rp_u,
                                          RE, Wkw, Wkb, Rt, cvec);
  bscatter_kernel<<<NCHK, 256, 0, stream>>>(edge_u, edge_i, enorm, bktcur, tmp_i, tmp_u);
  bsort_kernel<<<NBT, 256, 0, stream>>>(gbkt, bktbase, tmp_i, tmp_u,
                                        pair_i, pair_u, rp_i, rp_u);

  const float* u_cur = UE;
  const float* i_cur = IE;
  float* unext[2] = {uA, uB};
  float* inext[2] = {iA, iB};
  for (int l = 0; l < LAYERS; ++l) {
    layer_kernel<<<2048, 256, 0, stream>>>(
        EE, Rt + l * NRs * DD, cvec + l * NRs, kg_ent, kg_rel,
        Waw + (size_t)l * DD * DD, Wab + l * DD,
        Wbw + (size_t)l * DD * DD, Wbb + l * DD,
        rp_i, pair_i, rp_u, pair_u, u_cur, i_cur,
        inext[l], isum, (l == 0) ? IE : nullptr,
        unext[l], usum, (l == 0) ? UE : nullptr);
    u_cur = unext[l];
    i_cur = inext[l];
  }

  loss_kernel<<<256, 256, 0, stream>>>(usum, isum, user, pos, neg, acc, done, (float*)d_out);
}